// Round 3
// baseline (1623.849 us; speedup 1.0000x reference)
//
#include <hip/hip_runtime.h>

using uint = unsigned int;
using ushort = unsigned short;

typedef __attribute__((ext_vector_type(8))) short bf16x8;
typedef __attribute__((ext_vector_type(4))) float f32x4;

#define ADMM_ITERS 100
#define RHO_C 1.0f
#define SIGMA_C 1e-6f

__device__ inline ushort f2bf(float f) {
  union { float f; uint u; } c; c.f = f;
  uint u = c.u;
  uint r = (u + 0x7fffu + ((u >> 16) & 1u)) >> 16;
  return (ushort)r;
}

// ---------------------------------------------------------------------------
// f32 -> bf16 elementwise convert (4 elems/thread, float4 loads)
// ---------------------------------------------------------------------------
__global__ void convert_bf16(const float* __restrict__ in, ushort* __restrict__ out, int n4) {
  int i = blockIdx.x * blockDim.x + threadIdx.x;
  if (i >= n4) return;
  float4 v = ((const float4*)in)[i];
  uint2 p;
  p.x = (uint)f2bf(v.x) | ((uint)f2bf(v.y) << 16);
  p.y = (uint)f2bf(v.z) | ((uint)f2bf(v.w) << 16);
  ((uint2*)out)[i] = p;
}

// ---------------------------------------------------------------------------
// f32 transpose -> bf16: out[c][r] = bf16(in[r][c]); rows c in [C,Cout) zeroed.
// block 256 = 32x8, grid (ceil(Cout/32), ceil(R/32))
// ---------------------------------------------------------------------------
__global__ void transpose_f32_bf16(const float* __restrict__ in, ushort* __restrict__ out,
                                   int R, int C, int Cout) {
  __shared__ float t[32][33];
  const int c0 = blockIdx.x * 32, r0 = blockIdx.y * 32;
  const int tx = threadIdx.x & 31, ty = threadIdx.x >> 5;
  for (int rr = ty; rr < 32; rr += 8) {
    int r = r0 + rr, c = c0 + tx;
    float v = 0.0f;
    if (r < R && c < C) v = in[(long)r * C + c];
    t[rr][tx] = v;
  }
  __syncthreads();
  for (int rr = ty; rr < 32; rr += 8) {
    int c = c0 + rr, r = r0 + tx;
    if (c < Cout && r < R) out[(long)c * R + r] = f2bf(t[tx][rr]);
  }
}

// ---------------------------------------------------------------------------
// ADMM constants (all f32 inputs). cbuf layout (f32):
//   Minv[576] | A12[12*24] (Aeq rows 0-3, A rows 4-11) |
//   lc[12] | uc[12] | lb[24] | ub[24]           total 936
// Minv = inv((1+SIGMA+2*RHO)I + RHO*(Aeq^T Aeq + A^T A)) via Gauss-Jordan.
// ---------------------------------------------------------------------------
__global__ void setup_admm(const float* __restrict__ Aeq, const float* __restrict__ beq,
                           const float* __restrict__ A, const float* __restrict__ b,
                           const float* __restrict__ ub, const float* __restrict__ lb,
                           float* __restrict__ cbuf) {
  __shared__ float Aug[24][48];
  __shared__ float A12[12 * 24];
  __shared__ float fac[24];
  const int t = threadIdx.x;
  if (t < 96)  A12[t] = Aeq[t];          // rows 0-3
  if (t < 192) A12[96 + t] = A[t];       // rows 4-11
  __syncthreads();
  for (int idx = t; idx < 576; idx += 256) {
    int j = idx / 24, k = idx % 24;
    float s = (j == k) ? (1.0f + SIGMA_C + 2.0f * RHO_C) : 0.0f;
    for (int r = 0; r < 12; ++r) s += RHO_C * A12[r * 24 + j] * A12[r * 24 + k];
    Aug[j][k] = s;
    Aug[j][24 + k] = (j == k) ? 1.0f : 0.0f;
  }
  __syncthreads();
  for (int p = 0; p < 24; ++p) {
    float rp = 1.0f / Aug[p][p];               // stable: barrier ended prev phase
    if (t < 24) fac[t] = Aug[t][p];            // capture col p (pre-scale)
    __syncthreads();
    if (t < 48) Aug[p][t] *= rp;               // scale pivot row
    __syncthreads();
    for (int idx = t; idx < 24 * 48; idx += 256) {
      int r = idx / 48, c = idx % 48;
      if (r != p) Aug[r][c] -= fac[r] * Aug[p][c];
    }
    __syncthreads();
  }
  for (int idx = t; idx < 576; idx += 256) cbuf[idx] = Aug[idx / 24][24 + idx % 24];
  for (int idx = t; idx < 288; idx += 256) cbuf[576 + idx] = A12[idx];
  if (t < 12) {
    float lv, uv;
    if (t < 4) { lv = beq[t]; uv = lv; }
    else       { lv = -INFINITY; uv = b[t - 4]; }
    cbuf[864 + t] = lv;
    cbuf[876 + t] = uv;
  }
  if (t < 24) {
    cbuf[888 + t] = lb[t];
    cbuf[912 + t] = ub[t];
  }
}

// ---------------------------------------------------------------------------
// bf16 GEMM, C = A[M,K] * Bt[N,K]^T. Register staging (16B loads + ds_write),
// LDS row stride 40 elems (80B): per-b128 access, 64 lanes x 4 dwords spread
// exactly 8 dwords/bank (the wave64 floor) -> conflict-free.
// 16x16x32 bf16 MFMA. bias is f32.
// MODE 0: C bf16 +bias relu.  MODE 1: C f32 +bias, cols < nvalid only.
// block 256 (4 waves), grid (N/BN, M/BM)
// ---------------------------------------------------------------------------
template<int BM, int BN, int WM, int WN, int TM, int TN, int MODE>
__global__ __launch_bounds__(256) void gemm_bt(
    const ushort* __restrict__ A, const ushort* __restrict__ Bt,
    const float* __restrict__ bias, void* __restrict__ Cout_,
    int K, int ldc, int nvalid) {
  constexpr int LDE = 40;                       // LDS row stride in elements
  __shared__ __align__(16) ushort lds[(BM + BN) * LDE];
  ushort* ldsA = lds;
  ushort* ldsB = lds + BM * LDE;

  const int tid = threadIdx.x;
  const int wave = tid >> 6;
  const int lane = tid & 63;
  const int blockM = blockIdx.y * BM;
  const int blockN = blockIdx.x * BN;
  const int wm = (wave / WN) * (TM * 16);
  const int wn = (wave % WN) * (TN * 16);

  f32x4 acc[TM][TN] = {};

  const int l15 = lane & 15;
  const int kq = lane >> 4;
  constexpr int CHUNKS = (BM + BN) * 4;         // 16B chunks per K-tile

  for (int k0 = 0; k0 < K; k0 += 32) {
    for (int c = tid; c < CHUNKS; c += 256) {
      const int row = c >> 2, slot = c & 3;
      const ushort* src; int grow;
      if (row < BM) { src = A;  grow = blockM + row; }
      else          { src = Bt; grow = blockN + (row - BM); }
      bf16x8 v = *(const bf16x8*)(src + (long)grow * K + (k0 + slot * 8));
      *(bf16x8*)(lds + row * LDE + slot * 8) = v;
    }
    __syncthreads();

    bf16x8 af[TM], bfr[TN];
#pragma unroll
    for (int i = 0; i < TM; ++i)
      af[i] = *(const bf16x8*)(ldsA + (wm + i * 16 + l15) * LDE + kq * 8);
#pragma unroll
    for (int j = 0; j < TN; ++j)
      bfr[j] = *(const bf16x8*)(ldsB + (wn + j * 16 + l15) * LDE + kq * 8);
#pragma unroll
    for (int i = 0; i < TM; ++i)
#pragma unroll
      for (int j = 0; j < TN; ++j)
        acc[i][j] = __builtin_amdgcn_mfma_f32_16x16x32_bf16(af[i], bfr[j], acc[i][j], 0, 0, 0);
    __syncthreads();
  }

  const int ro = lane >> 4;
#pragma unroll
  for (int i = 0; i < TM; ++i) {
#pragma unroll
    for (int j = 0; j < TN; ++j) {
      const int col = blockN + wn + j * 16 + l15;
      float bv;
      if (MODE == 0) bv = bias[col];
      else bv = (col < nvalid) ? bias[col] : 0.0f;
#pragma unroll
      for (int r = 0; r < 4; ++r) {
        const int row = blockM + wm + i * 16 + ro * 4 + r;
        float v = acc[i][j][r] + bv;
        if (MODE == 0) {
          v = fmaxf(v, 0.0f);
          ((ushort*)Cout_)[(long)row * ldc + col] = f2bf(v);
        } else {
          if (col < nvalid) ((float*)Cout_)[(long)row * ldc + col] = v;
        }
      }
    }
  }
}

// ---------------------------------------------------------------------------
// ADMM, one lane per batch row, f32, state in VGPRs.
// I/-I mirror symmetry (Y_-=-Y_+, Z_-=-Z_+ by induction from 0 init):
// only 12 constraint rows + 24 box rows kept; box contributes 2*(rho*Zb-Yb).
// M = (1+sigma+2rho)I + rho*(Aeq^T Aeq + A^T A)  (handled in setup).
// rhs = raw + SIGMA*X + A12^T u_c + 2*u_b ;  X = Minv rhs ;
// constraint rows: s=A12 X ; box: s=X ; Zn=clip(s+Y,l,u); Y+=s-Zn.
// Constants from global via asm-opaqued SGPR pointer -> per-iter s_load
// batches (scalar pipe), no LICM register blowup.
// ---------------------------------------------------------------------------
__global__ __launch_bounds__(64, 1) void admm_kernel(
    const float* __restrict__ raw, const float* __restrict__ cbuf,
    float* __restrict__ outp) {
  const int row = blockIdx.x * 64 + threadIdx.x;
  float q[24];
  const float4* rp = (const float4*)(raw + (long)row * 24);
#pragma unroll
  for (int i = 0; i < 6; ++i) {
    float4 v = rp[i];
    q[i * 4 + 0] = v.x; q[i * 4 + 1] = v.y; q[i * 4 + 2] = v.z; q[i * 4 + 3] = v.w;
  }
  float X[24], Zb[24], Yb[24], Zc[12], Yc[12];
#pragma unroll
  for (int j = 0; j < 24; ++j) { X[j] = 0.0f; Zb[j] = 0.0f; Yb[j] = 0.0f; }
#pragma unroll
  for (int r = 0; r < 12; ++r) { Zc[r] = 0.0f; Yc[r] = 0.0f; }

  const float* cb = cbuf;
#pragma unroll 1
  for (int it = 0; it < ADMM_ITERS; ++it) {
    asm volatile("" : "+s"(cb));              // block LICM of constant loads
    const float* Minv = cb;
    const float* A12a = cb + 576;
    float ucv[12];
#pragma unroll
    for (int r = 0; r < 12; ++r) ucv[r] = RHO_C * Zc[r] - Yc[r];
    float rhs[24];
#pragma unroll
    for (int j = 0; j < 24; ++j)
      rhs[j] = q[j] + SIGMA_C * X[j] + 2.0f * (RHO_C * Zb[j] - Yb[j]);
#pragma unroll
    for (int r = 0; r < 12; ++r)
#pragma unroll
      for (int j = 0; j < 24; ++j)
        rhs[j] += ucv[r] * A12a[r * 24 + j];
    // X = Minv * rhs  (Minv symmetric)
#pragma unroll
    for (int j = 0; j < 24; ++j) {
      float s = 0.0f;
#pragma unroll
      for (int k = 0; k < 24; ++k) s += Minv[j * 24 + k] * rhs[k];
      X[j] = s;
    }
    asm volatile("" : "+s"(cb));              // re-opaque: no cross-phase CSE
    const float* A12b = cb + 576;
    const float* lc  = cb + 864;
    const float* uc  = cb + 876;
    const float* lbv = cb + 888;
    const float* ubv = cb + 912;
#pragma unroll
    for (int r = 0; r < 12; ++r) {
      float s = 0.0f;
#pragma unroll
      for (int j = 0; j < 24; ++j) s += A12b[r * 24 + j] * X[j];
      float zn = fminf(fmaxf(s + Yc[r] / RHO_C, lc[r]), uc[r]);
      Yc[r] += RHO_C * (s - zn);
      Zc[r] = zn;
    }
#pragma unroll
    for (int j = 0; j < 24; ++j) {
      float s = X[j];
      float zn = fminf(fmaxf(s + Yb[j] / RHO_C, lbv[j]), ubv[j]);
      Yb[j] += RHO_C * (s - zn);
      Zb[j] = zn;
    }
  }
  float4* op = (float4*)(outp + (long)row * 24);
#pragma unroll
  for (int i = 0; i < 6; ++i)
    op[i] = make_float4(X[4 * i], X[4 * i + 1], X[4 * i + 2], X[4 * i + 3]);
}

// ---------------------------------------------------------------------------
extern "C" void kernel_launch(void* const* d_in, const int* in_sizes, int n_in,
                              void* d_out, int out_size, void* d_ws, size_t ws_size,
                              hipStream_t stream) {
  const float* state = (const float*)d_in[0];
  const float* Aeq   = (const float*)d_in[1];
  const float* beq   = (const float*)d_in[2];
  const float* Ain   = (const float*)d_in[3];
  const float* bin   = (const float*)d_in[4];
  const float* ub    = (const float*)d_in[5];
  const float* lb    = (const float*)d_in[6];
  const float* W1    = (const float*)d_in[7];
  const float* b1    = (const float*)d_in[8];
  const float* W2    = (const float*)d_in[9];
  const float* b2    = (const float*)d_in[10];
  const float* W3    = (const float*)d_in[11];
  const float* b3    = (const float*)d_in[12];

  const int Bn = in_sizes[0] / 512;            // 16384
  char* ws = (char*)d_ws;
  ushort* stateB = (ushort*)(ws + 0);          // 16384x512 bf16  (16 MB)
  ushort* W1T    = (ushort*)(ws + 16777216);   // 1024x512        (1 MB)
  ushort* W2T    = (ushort*)(ws + 17825792);   // 1024x1024       (2 MB)
  ushort* W3T    = (ushort*)(ws + 19922944);   // 32x1024 (rows>=24 zero)
  float*  cbuf   = (float*) (ws + 19988480);   // 936 f32
  float*  rawb   = (float*) (ws + 19992576);   // 16384x24 f32    (1.5 MB)
  ushort* H1     = (ushort*)(ws + 21565440);   // 16384x1024 bf16 (32 MB)
  ushort* H2     = (ushort*)(ws + 55119872);   // 16384x1024 bf16 (32 MB)

  const int n4 = (Bn * 512) / 4;
  convert_bf16<<<(n4 + 255) / 256, 256, 0, stream>>>(state, stateB, n4);
  transpose_f32_bf16<<<dim3(32, 16), 256, 0, stream>>>(W1, W1T, 512, 1024, 1024);
  transpose_f32_bf16<<<dim3(32, 32), 256, 0, stream>>>(W2, W2T, 1024, 1024, 1024);
  transpose_f32_bf16<<<dim3(1, 32),  256, 0, stream>>>(W3, W3T, 1024, 24, 32);
  setup_admm<<<1, 256, 0, stream>>>(Aeq, beq, Ain, bin, ub, lb, cbuf);

  gemm_bt<128, 128, 2, 2, 4, 4, 0><<<dim3(8, Bn / 128), 256, 0, stream>>>(
      stateB, W1T, b1, H1, 512, 1024, 1024);
  gemm_bt<128, 128, 2, 2, 4, 4, 0><<<dim3(8, Bn / 128), 256, 0, stream>>>(
      H1, W2T, b2, H2, 1024, 1024, 1024);
  gemm_bt<128, 32, 4, 1, 2, 2, 1><<<dim3(1, Bn / 128), 256, 0, stream>>>(
      H2, W3T, b3, rawb, 1024, 24, 24);

  admm_kernel<<<Bn / 64, 64, 0, stream>>>(rawb, cbuf, (float*)d_out);
}

// Round 4
// 1395.298 us; speedup vs baseline: 1.1638x; 1.1638x over previous
//
#include <hip/hip_runtime.h>

using uint = unsigned int;
using ushort = unsigned short;

typedef __attribute__((ext_vector_type(8))) short bf16x8;
typedef __attribute__((ext_vector_type(4))) float f32x4;

#define ADMM_ITERS 100
#define RHO_C 1.0f
#define SIGMA_C 1e-6f

__device__ inline ushort f2bf(float f) {
  union { float f; uint u; } c; c.f = f;
  uint u = c.u;
  uint r = (u + 0x7fffu + ((u >> 16) & 1u)) >> 16;
  return (ushort)r;
}

// ---------------------------------------------------------------------------
// f32 -> bf16 elementwise convert (4 elems/thread, float4 loads)
// ---------------------------------------------------------------------------
__global__ void convert_bf16(const float* __restrict__ in, ushort* __restrict__ out, int n4) {
  int i = blockIdx.x * blockDim.x + threadIdx.x;
  if (i >= n4) return;
  float4 v = ((const float4*)in)[i];
  uint2 p;
  p.x = (uint)f2bf(v.x) | ((uint)f2bf(v.y) << 16);
  p.y = (uint)f2bf(v.z) | ((uint)f2bf(v.w) << 16);
  ((uint2*)out)[i] = p;
}

// ---------------------------------------------------------------------------
// f32 transpose -> bf16: out[c][r] = bf16(in[r][c]); rows c in [C,Cout) zeroed.
// block 256 = 32x8, grid (ceil(Cout/32), ceil(R/32))
// ---------------------------------------------------------------------------
__global__ void transpose_f32_bf16(const float* __restrict__ in, ushort* __restrict__ out,
                                   int R, int C, int Cout) {
  __shared__ float t[32][33];
  const int c0 = blockIdx.x * 32, r0 = blockIdx.y * 32;
  const int tx = threadIdx.x & 31, ty = threadIdx.x >> 5;
  for (int rr = ty; rr < 32; rr += 8) {
    int r = r0 + rr, c = c0 + tx;
    float v = 0.0f;
    if (r < R && c < C) v = in[(long)r * C + c];
    t[rr][tx] = v;
  }
  __syncthreads();
  for (int rr = ty; rr < 32; rr += 8) {
    int c = c0 + rr, r = r0 + tx;
    if (c < Cout && r < R) out[(long)c * R + r] = f2bf(t[tx][rr]);
  }
}

// ---------------------------------------------------------------------------
// ADMM constants (all f32 inputs). cbuf layout (f32):
//   Minv[576] | A12[12*24] (Aeq rows 0-3, A rows 4-11) |
//   lc[12] | uc[12] | lb[24] | ub[24]           total 936
// Minv = inv((1+SIGMA+2*RHO)I + RHO*(Aeq^T Aeq + A^T A)) via Gauss-Jordan.
// ---------------------------------------------------------------------------
__global__ void setup_admm(const float* __restrict__ Aeq, const float* __restrict__ beq,
                           const float* __restrict__ A, const float* __restrict__ b,
                           const float* __restrict__ ub, const float* __restrict__ lb,
                           float* __restrict__ cbuf) {
  __shared__ float Aug[24][48];
  __shared__ float A12[12 * 24];
  __shared__ float fac[24];
  const int t = threadIdx.x;
  if (t < 96)  A12[t] = Aeq[t];          // rows 0-3
  if (t < 192) A12[96 + t] = A[t];       // rows 4-11
  __syncthreads();
  for (int idx = t; idx < 576; idx += 256) {
    int j = idx / 24, k = idx % 24;
    float s = (j == k) ? (1.0f + SIGMA_C + 2.0f * RHO_C) : 0.0f;
    for (int r = 0; r < 12; ++r) s += RHO_C * A12[r * 24 + j] * A12[r * 24 + k];
    Aug[j][k] = s;
    Aug[j][24 + k] = (j == k) ? 1.0f : 0.0f;
  }
  __syncthreads();
  for (int p = 0; p < 24; ++p) {
    float rp = 1.0f / Aug[p][p];               // stable: barrier ended prev phase
    if (t < 24) fac[t] = Aug[t][p];            // capture col p (pre-scale)
    __syncthreads();
    if (t < 48) Aug[p][t] *= rp;               // scale pivot row
    __syncthreads();
    for (int idx = t; idx < 24 * 48; idx += 256) {
      int r = idx / 48, c = idx % 48;
      if (r != p) Aug[r][c] -= fac[r] * Aug[p][c];
    }
    __syncthreads();
  }
  for (int idx = t; idx < 576; idx += 256) cbuf[idx] = Aug[idx / 24][24 + idx % 24];
  for (int idx = t; idx < 288; idx += 256) cbuf[576 + idx] = A12[idx];
  if (t < 12) {
    float lv, uv;
    if (t < 4) { lv = beq[t]; uv = lv; }
    else       { lv = -INFINITY; uv = b[t - 4]; }
    cbuf[864 + t] = lv;
    cbuf[876 + t] = uv;
  }
  if (t < 24) {
    cbuf[888 + t] = lb[t];
    cbuf[912 + t] = ub[t];
  }
}

// ---------------------------------------------------------------------------
// bf16 GEMM, C = A[M,K] * Bt[N,K]^T. Register staging (16B loads + ds_write),
// LDS row stride 40 elems (80B): conflict-free b128 reads/writes.
// 16x16x32 bf16 MFMA. bias is f32.
// MODE 0: C bf16 +bias relu.  MODE 1: C f32 +bias, cols < nvalid only.
// block 256 (4 waves), grid (N/BN, M/BM)
// ---------------------------------------------------------------------------
template<int BM, int BN, int WM, int WN, int TM, int TN, int MODE>
__global__ __launch_bounds__(256) void gemm_bt(
    const ushort* __restrict__ A, const ushort* __restrict__ Bt,
    const float* __restrict__ bias, void* __restrict__ Cout_,
    int K, int ldc, int nvalid) {
  constexpr int LDE = 40;                       // LDS row stride in elements
  __shared__ __align__(16) ushort lds[(BM + BN) * LDE];
  ushort* ldsA = lds;
  ushort* ldsB = lds + BM * LDE;

  const int tid = threadIdx.x;
  const int wave = tid >> 6;
  const int lane = tid & 63;
  const int blockM = blockIdx.y * BM;
  const int blockN = blockIdx.x * BN;
  const int wm = (wave / WN) * (TM * 16);
  const int wn = (wave % WN) * (TN * 16);

  f32x4 acc[TM][TN] = {};

  const int l15 = lane & 15;
  const int kq = lane >> 4;
  constexpr int CHUNKS = (BM + BN) * 4;         // 16B chunks per K-tile

  for (int k0 = 0; k0 < K; k0 += 32) {
    for (int c = tid; c < CHUNKS; c += 256) {
      const int row = c >> 2, slot = c & 3;
      const ushort* src; int grow;
      if (row < BM) { src = A;  grow = blockM + row; }
      else          { src = Bt; grow = blockN + (row - BM); }
      bf16x8 v = *(const bf16x8*)(src + (long)grow * K + (k0 + slot * 8));
      *(bf16x8*)(lds + row * LDE + slot * 8) = v;
    }
    __syncthreads();

    bf16x8 af[TM], bfr[TN];
#pragma unroll
    for (int i = 0; i < TM; ++i)
      af[i] = *(const bf16x8*)(ldsA + (wm + i * 16 + l15) * LDE + kq * 8);
#pragma unroll
    for (int j = 0; j < TN; ++j)
      bfr[j] = *(const bf16x8*)(ldsB + (wn + j * 16 + l15) * LDE + kq * 8);
#pragma unroll
    for (int i = 0; i < TM; ++i)
#pragma unroll
      for (int j = 0; j < TN; ++j)
        acc[i][j] = __builtin_amdgcn_mfma_f32_16x16x32_bf16(af[i], bfr[j], acc[i][j], 0, 0, 0);
    __syncthreads();
  }

  const int ro = lane >> 4;
#pragma unroll
  for (int i = 0; i < TM; ++i) {
#pragma unroll
    for (int j = 0; j < TN; ++j) {
      const int col = blockN + wn + j * 16 + l15;
      float bv;
      if (MODE == 0) bv = bias[col];
      else bv = (col < nvalid) ? bias[col] : 0.0f;
#pragma unroll
      for (int r = 0; r < 4; ++r) {
        const int row = blockM + wm + i * 16 + ro * 4 + r;
        float v = acc[i][j][r] + bv;
        if (MODE == 0) {
          v = fmaxf(v, 0.0f);
          ((ushort*)Cout_)[(long)row * ldc + col] = f2bf(v);
        } else {
          if (col < nvalid) ((float*)Cout_)[(long)row * ldc + col] = v;
        }
      }
    }
  }
}

// ---------------------------------------------------------------------------
// ADMM, one lane per batch row, f32, all state in VGPRs.
// amdgpu_waves_per_eu(1): license the allocator to ~512 VGPRs -- round-3
// counters showed VGPR_Count=80 with ~0.9 GB scratch-spill traffic.
// Constants staged once into LDS; per-iter reads are uniform-address
// (broadcast, conflict-free) ds_reads. asm-opaqued offset defeats LICM
// (which would hoist 936 loads into registers and re-cause spilling).
// I/-I mirror symmetry: only 12 constraint rows + 24 box rows kept.
// ---------------------------------------------------------------------------
__global__ __launch_bounds__(64) __attribute__((amdgpu_waves_per_eu(1)))
void admm_kernel(const float* __restrict__ raw, const float* __restrict__ cbuf,
                 float* __restrict__ outp) {
  __shared__ float clds[936];
  const int tid = threadIdx.x;
  for (int i = tid; i < 936; i += 64) clds[i] = cbuf[i];
  __syncthreads();

  const int row = blockIdx.x * 64 + tid;
  float q[24];
  const float4* rp = (const float4*)(raw + (long)row * 24);
#pragma unroll
  for (int i = 0; i < 6; ++i) {
    float4 v = rp[i];
    q[i * 4 + 0] = v.x; q[i * 4 + 1] = v.y; q[i * 4 + 2] = v.z; q[i * 4 + 3] = v.w;
  }
  float X[24], Zb[24], Yb[24], Zc[12], Yc[12];
#pragma unroll
  for (int j = 0; j < 24; ++j) { X[j] = 0.0f; Zb[j] = 0.0f; Yb[j] = 0.0f; }
#pragma unroll
  for (int r = 0; r < 12; ++r) { Zc[r] = 0.0f; Yc[r] = 0.0f; }

  int coff = 0;
#pragma unroll 1
  for (int it = 0; it < ADMM_ITERS; ++it) {
    asm volatile("" : "+v"(coff));            // block LICM of constant loads
    const float* Minv = clds + coff;
    const float* A12a = clds + coff + 576;
    float ucv[12];
#pragma unroll
    for (int r = 0; r < 12; ++r) ucv[r] = RHO_C * Zc[r] - Yc[r];
    float rhs[24];
#pragma unroll
    for (int j = 0; j < 24; ++j)
      rhs[j] = q[j] + SIGMA_C * X[j] + 2.0f * (RHO_C * Zb[j] - Yb[j]);
#pragma unroll
    for (int r = 0; r < 12; ++r)
#pragma unroll
      for (int j = 0; j < 24; ++j)
        rhs[j] += ucv[r] * A12a[r * 24 + j];
    // X = Minv * rhs
#pragma unroll
    for (int j = 0; j < 24; ++j) {
      float s = 0.0f;
#pragma unroll
      for (int k = 0; k < 24; ++k) s += Minv[j * 24 + k] * rhs[k];
      X[j] = s;
    }
    asm volatile("" : "+v"(coff));            // re-opaque: no cross-phase CSE
    const float* A12b = clds + coff + 576;
    const float* lc  = clds + coff + 864;
    const float* uc  = clds + coff + 876;
    const float* lbv = clds + coff + 888;
    const float* ubv = clds + coff + 912;
#pragma unroll
    for (int r = 0; r < 12; ++r) {
      float s = 0.0f;
#pragma unroll
      for (int j = 0; j < 24; ++j) s += A12b[r * 24 + j] * X[j];
      float zn = fminf(fmaxf(s + Yc[r], lc[r]), uc[r]);   // rho = 1
      Yc[r] += s - zn;
      Zc[r] = zn;
    }
#pragma unroll
    for (int j = 0; j < 24; ++j) {
      float s = X[j];
      float zn = fminf(fmaxf(s + Yb[j], lbv[j]), ubv[j]);
      Yb[j] += s - zn;
      Zb[j] = zn;
    }
  }
  float4* op = (float4*)(outp + (long)row * 24);
#pragma unroll
  for (int i = 0; i < 6; ++i)
    op[i] = make_float4(X[4 * i], X[4 * i + 1], X[4 * i + 2], X[4 * i + 3]);
}

// ---------------------------------------------------------------------------
extern "C" void kernel_launch(void* const* d_in, const int* in_sizes, int n_in,
                              void* d_out, int out_size, void* d_ws, size_t ws_size,
                              hipStream_t stream) {
  const float* state = (const float*)d_in[0];
  const float* Aeq   = (const float*)d_in[1];
  const float* beq   = (const float*)d_in[2];
  const float* Ain   = (const float*)d_in[3];
  const float* bin   = (const float*)d_in[4];
  const float* ub    = (const float*)d_in[5];
  const float* lb    = (const float*)d_in[6];
  const float* W1    = (const float*)d_in[7];
  const float* b1    = (const float*)d_in[8];
  const float* W2    = (const float*)d_in[9];
  const float* b2    = (const float*)d_in[10];
  const float* W3    = (const float*)d_in[11];
  const float* b3    = (const float*)d_in[12];

  const int Bn = in_sizes[0] / 512;            // 16384
  char* ws = (char*)d_ws;
  ushort* stateB = (ushort*)(ws + 0);          // 16384x512 bf16  (16 MB)
  ushort* W1T    = (ushort*)(ws + 16777216);   // 1024x512        (1 MB)
  ushort* W2T    = (ushort*)(ws + 17825792);   // 1024x1024       (2 MB)
  ushort* W3T    = (ushort*)(ws + 19922944);   // 32x1024 (rows>=24 zero)
  float*  cbuf   = (float*) (ws + 19988480);   // 936 f32
  float*  rawb   = (float*) (ws + 19992576);   // 16384x24 f32    (1.5 MB)
  ushort* H1     = (ushort*)(ws + 21565440);   // 16384x1024 bf16 (32 MB)
  ushort* H2     = (ushort*)(ws + 55119872);   // 16384x1024 bf16 (32 MB)

  const int n4 = (Bn * 512) / 4;
  convert_bf16<<<(n4 + 255) / 256, 256, 0, stream>>>(state, stateB, n4);
  transpose_f32_bf16<<<dim3(32, 16), 256, 0, stream>>>(W1, W1T, 512, 1024, 1024);
  transpose_f32_bf16<<<dim3(32, 32), 256, 0, stream>>>(W2, W2T, 1024, 1024, 1024);
  transpose_f32_bf16<<<dim3(1, 32),  256, 0, stream>>>(W3, W3T, 1024, 24, 32);
  setup_admm<<<1, 256, 0, stream>>>(Aeq, beq, Ain, bin, ub, lb, cbuf);

  gemm_bt<128, 128, 2, 2, 4, 4, 0><<<dim3(8, Bn / 128), 256, 0, stream>>>(
      stateB, W1T, b1, H1, 512, 1024, 1024);
  gemm_bt<128, 128, 2, 2, 4, 4, 0><<<dim3(8, Bn / 128), 256, 0, stream>>>(
      H1, W2T, b2, H2, 1024, 1024, 1024);
  gemm_bt<64, 32, 4, 1, 1, 2, 1><<<dim3(1, Bn / 64), 256, 0, stream>>>(
      H2, W3T, b3, rawb, 1024, 24, 24);

  admm_kernel<<<Bn / 64, 64, 0, stream>>>(rawb, cbuf, (float*)d_out);
}

// Round 5
// 819.571 us; speedup vs baseline: 1.9813x; 1.7025x over previous
//
#include <hip/hip_runtime.h>

using uint = unsigned int;
using ushort = unsigned short;

typedef __attribute__((ext_vector_type(8))) short bf16x8;
typedef __attribute__((ext_vector_type(4))) float f32x4;
using cfp = const __attribute__((address_space(4))) float*;   // SMEM (s_load) path

#define ADMM_ITERS 100
#define RHO_C 1.0f
#define SIGMA_C 1e-6f

__device__ inline ushort f2bf(float f) {
  union { float f; uint u; } c; c.f = f;
  uint u = c.u;
  uint r = (u + 0x7fffu + ((u >> 16) & 1u)) >> 16;
  return (ushort)r;
}

// ---------------------------------------------------------------------------
// f32 -> bf16 elementwise convert (4 elems/thread, float4 loads)
// ---------------------------------------------------------------------------
__global__ void convert_bf16(const float* __restrict__ in, ushort* __restrict__ out, int n4) {
  int i = blockIdx.x * blockDim.x + threadIdx.x;
  if (i >= n4) return;
  float4 v = ((const float4*)in)[i];
  uint2 p;
  p.x = (uint)f2bf(v.x) | ((uint)f2bf(v.y) << 16);
  p.y = (uint)f2bf(v.z) | ((uint)f2bf(v.w) << 16);
  ((uint2*)out)[i] = p;
}

// ---------------------------------------------------------------------------
// f32 transpose -> bf16: out[c][r] = bf16(in[r][c]); rows c in [C,Cout) zeroed.
// block 256 = 32x8, grid (ceil(Cout/32), ceil(R/32))
// ---------------------------------------------------------------------------
__global__ void transpose_f32_bf16(const float* __restrict__ in, ushort* __restrict__ out,
                                   int R, int C, int Cout) {
  __shared__ float t[32][33];
  const int c0 = blockIdx.x * 32, r0 = blockIdx.y * 32;
  const int tx = threadIdx.x & 31, ty = threadIdx.x >> 5;
  for (int rr = ty; rr < 32; rr += 8) {
    int r = r0 + rr, c = c0 + tx;
    float v = 0.0f;
    if (r < R && c < C) v = in[(long)r * C + c];
    t[rr][tx] = v;
  }
  __syncthreads();
  for (int rr = ty; rr < 32; rr += 8) {
    int c = c0 + rr, r = r0 + tx;
    if (c < Cout && r < R) out[(long)c * R + r] = f2bf(t[tx][rr]);
  }
}

// ---------------------------------------------------------------------------
// ADMM constants (all f32 inputs), written to TWO identical buffers (the admm
// kernel ping-pongs between them so constant addresses are loop-variant ->
// LICM cannot hoist 936 loads). Layout (f32):
//   Minv[576] | A12[12*24] (Aeq rows 0-3, A rows 4-11) |
//   lc[12] | uc[12] | lb[24] | ub[24]           total 936
// Minv = inv((1+SIGMA+2*RHO)I + RHO*(Aeq^T Aeq + A^T A)) via Gauss-Jordan.
// ---------------------------------------------------------------------------
__global__ void setup_admm(const float* __restrict__ Aeq, const float* __restrict__ beq,
                           const float* __restrict__ A, const float* __restrict__ b,
                           const float* __restrict__ ub, const float* __restrict__ lb,
                           float* __restrict__ cbuf, float* __restrict__ cbuf2) {
  __shared__ float Aug[24][48];
  __shared__ float A12[12 * 24];
  __shared__ float fac[24];
  const int t = threadIdx.x;
  if (t < 96)  A12[t] = Aeq[t];          // rows 0-3
  if (t < 192) A12[96 + t] = A[t];       // rows 4-11
  __syncthreads();
  for (int idx = t; idx < 576; idx += 256) {
    int j = idx / 24, k = idx % 24;
    float s = (j == k) ? (1.0f + SIGMA_C + 2.0f * RHO_C) : 0.0f;
    for (int r = 0; r < 12; ++r) s += RHO_C * A12[r * 24 + j] * A12[r * 24 + k];
    Aug[j][k] = s;
    Aug[j][24 + k] = (j == k) ? 1.0f : 0.0f;
  }
  __syncthreads();
  for (int p = 0; p < 24; ++p) {
    float rp = 1.0f / Aug[p][p];               // stable: barrier ended prev phase
    if (t < 24) fac[t] = Aug[t][p];            // capture col p (pre-scale)
    __syncthreads();
    if (t < 48) Aug[p][t] *= rp;               // scale pivot row
    __syncthreads();
    for (int idx = t; idx < 24 * 48; idx += 256) {
      int r = idx / 48, c = idx % 48;
      if (r != p) Aug[r][c] -= fac[r] * Aug[p][c];
    }
    __syncthreads();
  }
  for (int idx = t; idx < 576; idx += 256) {
    float v = Aug[idx / 24][24 + idx % 24];
    cbuf[idx] = v; cbuf2[idx] = v;
  }
  for (int idx = t; idx < 288; idx += 256) {
    float v = A12[idx];
    cbuf[576 + idx] = v; cbuf2[576 + idx] = v;
  }
  if (t < 12) {
    float lv, uv;
    if (t < 4) { lv = beq[t]; uv = lv; }
    else       { lv = -INFINITY; uv = b[t - 4]; }
    cbuf[864 + t] = lv;  cbuf2[864 + t] = lv;
    cbuf[876 + t] = uv;  cbuf2[876 + t] = uv;
  }
  if (t < 24) {
    cbuf[888 + t] = lb[t];  cbuf2[888 + t] = lb[t];
    cbuf[912 + t] = ub[t];  cbuf2[912 + t] = ub[t];
  }
}

// ---------------------------------------------------------------------------
// bf16 GEMM, C = A[M,K] * Bt[N,K]^T. Register staging (16B loads + ds_write),
// LDS row stride 40 elems (80B): conflict-free b128 reads/writes.
// 16x16x32 bf16 MFMA. bias is f32.
// MODE 0: C bf16 +bias relu.  MODE 1: C f32 +bias, cols < nvalid only.
// block 256 (4 waves), grid (N/BN, M/BM)
// ---------------------------------------------------------------------------
template<int BM, int BN, int WM, int WN, int TM, int TN, int MODE>
__global__ __launch_bounds__(256) void gemm_bt(
    const ushort* __restrict__ A, const ushort* __restrict__ Bt,
    const float* __restrict__ bias, void* __restrict__ Cout_,
    int K, int ldc, int nvalid) {
  constexpr int LDE = 40;                       // LDS row stride in elements
  __shared__ __align__(16) ushort lds[(BM + BN) * LDE];
  ushort* ldsA = lds;
  ushort* ldsB = lds + BM * LDE;

  const int tid = threadIdx.x;
  const int wave = tid >> 6;
  const int lane = tid & 63;
  const int blockM = blockIdx.y * BM;
  const int blockN = blockIdx.x * BN;
  const int wm = (wave / WN) * (TM * 16);
  const int wn = (wave % WN) * (TN * 16);

  f32x4 acc[TM][TN] = {};

  const int l15 = lane & 15;
  const int kq = lane >> 4;
  constexpr int CHUNKS = (BM + BN) * 4;         // 16B chunks per K-tile

  for (int k0 = 0; k0 < K; k0 += 32) {
    for (int c = tid; c < CHUNKS; c += 256) {
      const int row = c >> 2, slot = c & 3;
      const ushort* src; int grow;
      if (row < BM) { src = A;  grow = blockM + row; }
      else          { src = Bt; grow = blockN + (row - BM); }
      bf16x8 v = *(const bf16x8*)(src + (long)grow * K + (k0 + slot * 8));
      *(bf16x8*)(lds + row * LDE + slot * 8) = v;
    }
    __syncthreads();

    bf16x8 af[TM], bfr[TN];
#pragma unroll
    for (int i = 0; i < TM; ++i)
      af[i] = *(const bf16x8*)(ldsA + (wm + i * 16 + l15) * LDE + kq * 8);
#pragma unroll
    for (int j = 0; j < TN; ++j)
      bfr[j] = *(const bf16x8*)(ldsB + (wn + j * 16 + l15) * LDE + kq * 8);
#pragma unroll
    for (int i = 0; i < TM; ++i)
#pragma unroll
      for (int j = 0; j < TN; ++j)
        acc[i][j] = __builtin_amdgcn_mfma_f32_16x16x32_bf16(af[i], bfr[j], acc[i][j], 0, 0, 0);
    __syncthreads();
  }

  const int ro = lane >> 4;
#pragma unroll
  for (int i = 0; i < TM; ++i) {
#pragma unroll
    for (int j = 0; j < TN; ++j) {
      const int col = blockN + wn + j * 16 + l15;
      float bv;
      if (MODE == 0) bv = bias[col];
      else bv = (col < nvalid) ? bias[col] : 0.0f;
#pragma unroll
      for (int r = 0; r < 4; ++r) {
        const int row = blockM + wm + i * 16 + ro * 4 + r;
        float v = acc[i][j][r] + bv;
        if (MODE == 0) {
          v = fmaxf(v, 0.0f);
          ((ushort*)Cout_)[(long)row * ldc + col] = f2bf(v);
        } else {
          if (col < nvalid) ((float*)Cout_)[(long)row * ldc + col] = v;
        }
      }
    }
  }
}

// ---------------------------------------------------------------------------
// ADMM, one lane per batch row, f32, all state in VGPRs.
// NO inline asm (round 3/4 post-mortem: asm volatile blocked alloca promotion
// -> all state lived in scratch, 1.5 GB spill traffic, VGPR_Count stuck ~84).
// LICM of the 936 constant loads is prevented STRUCTURALLY: two identical
// constant buffers, pointer ping-pong each iteration (PHI -> loop-variant
// addresses). Constants are wave-uniform, read through address_space(4)
// (scalar cache, s_load) and consumed as the 1-SGPR operand of v_fmac_f32.
// Phase 1 reads copy A, phase 3 copy B -> no cross-phase CSE holding 288
// values live. raw may alias outp (thread-private row: read fully, written
// at end).  I/-I mirror symmetry: 12 constraint rows + 24 box rows kept.
// ---------------------------------------------------------------------------
__global__ __launch_bounds__(64) __attribute__((amdgpu_waves_per_eu(1)))
void admm_kernel(const float* raw, const float* __restrict__ cbufA,
                 const float* __restrict__ cbufB, float* outp) {
  const int row = blockIdx.x * 64 + threadIdx.x;
  float q[24];
  const float4* rp = (const float4*)(raw + (long)row * 24);
#pragma unroll
  for (int i = 0; i < 6; ++i) {
    float4 v = rp[i];
    q[i * 4 + 0] = v.x; q[i * 4 + 1] = v.y; q[i * 4 + 2] = v.z; q[i * 4 + 3] = v.w;
  }
  float X[24], Zb[24], Yb[24], Zc[12], Yc[12];
#pragma unroll
  for (int j = 0; j < 24; ++j) { X[j] = 0.0f; Zb[j] = 0.0f; Yb[j] = 0.0f; }
#pragma unroll
  for (int r = 0; r < 12; ++r) { Zc[r] = 0.0f; Yc[r] = 0.0f; }

  const float* pa = cbufA;
  const float* pb = cbufB;
#pragma unroll 1
  for (int it = 0; it < ADMM_ITERS; ++it) {
    cfp Minv = (cfp)pa;                   // phase-1 constants from copy A
    cfp A12a = (cfp)(pa + 576);
    float ucv[12];
#pragma unroll
    for (int r = 0; r < 12; ++r) ucv[r] = RHO_C * Zc[r] - Yc[r];
    float rhs[24];
#pragma unroll
    for (int j = 0; j < 24; ++j)
      rhs[j] = q[j] + SIGMA_C * X[j] + 2.0f * (RHO_C * Zb[j] - Yb[j]);
#pragma unroll
    for (int r = 0; r < 12; ++r)
#pragma unroll
      for (int j = 0; j < 24; ++j)
        rhs[j] += ucv[r] * A12a[r * 24 + j];
    // X = Minv * rhs
#pragma unroll
    for (int j = 0; j < 24; ++j) {
      float s = 0.0f;
#pragma unroll
      for (int k = 0; k < 24; ++k) s += Minv[j * 24 + k] * rhs[k];
      X[j] = s;
    }
    cfp A12b = (cfp)(pb + 576);           // phase-3 constants from copy B
    cfp lc   = (cfp)(pb + 864);
    cfp uc   = (cfp)(pb + 876);
    cfp lbv  = (cfp)(pb + 888);
    cfp ubv  = (cfp)(pb + 912);
#pragma unroll
    for (int r = 0; r < 12; ++r) {
      float s = 0.0f;
#pragma unroll
      for (int j = 0; j < 24; ++j) s += A12b[r * 24 + j] * X[j];
      float zn = fminf(fmaxf(s + Yc[r], lc[r]), uc[r]);   // rho = 1
      Yc[r] += s - zn;
      Zc[r] = zn;
    }
#pragma unroll
    for (int j = 0; j < 24; ++j) {
      float s = X[j];
      float zn = fminf(fmaxf(s + Yb[j], lbv[j]), ubv[j]);
      Yb[j] += s - zn;
      Zb[j] = zn;
    }
    const float* tsw = pa; pa = pb; pb = tsw;   // ping-pong -> loop-variant
  }
  float4* op = (float4*)(outp + (long)row * 24);
#pragma unroll
  for (int i = 0; i < 6; ++i)
    op[i] = make_float4(X[4 * i], X[4 * i + 1], X[4 * i + 2], X[4 * i + 3]);
}

// ---------------------------------------------------------------------------
extern "C" void kernel_launch(void* const* d_in, const int* in_sizes, int n_in,
                              void* d_out, int out_size, void* d_ws, size_t ws_size,
                              hipStream_t stream) {
  const float* state = (const float*)d_in[0];
  const float* Aeq   = (const float*)d_in[1];
  const float* beq   = (const float*)d_in[2];
  const float* Ain   = (const float*)d_in[3];
  const float* bin   = (const float*)d_in[4];
  const float* ub    = (const float*)d_in[5];
  const float* lb    = (const float*)d_in[6];
  const float* W1    = (const float*)d_in[7];
  const float* b1    = (const float*)d_in[8];
  const float* W2    = (const float*)d_in[9];
  const float* b2    = (const float*)d_in[10];
  const float* W3    = (const float*)d_in[11];
  const float* b3    = (const float*)d_in[12];

  const int Bn = in_sizes[0] / 512;            // 16384
  char* ws = (char*)d_ws;
  ushort* stateB = (ushort*)(ws + 0);          // 16384x512 bf16  (16 MB)
  ushort* W1T    = (ushort*)(ws + 16777216);   // 1024x512        (1 MB)
  ushort* W2T    = (ushort*)(ws + 17825792);   // 1024x1024       (2 MB)
  ushort* W3T    = (ushort*)(ws + 19922944);   // 32x1024 (rows>=24 zero)
  float*  cbuf   = (float*) (ws + 19988480);   // 936 f32 (copy A)
  float*  cbuf2  = (float*) (ws + 19992576);   // 936 f32 (copy B)
  ushort* H1     = (ushort*)(ws + 21565440);   // 16384x1024 bf16 (32 MB)
  ushort* H2     = (ushort*)(ws + 55119872);   // 16384x1024 bf16 (32 MB)
  float*  rawb   = (float*)d_out;              // gemm3 output = admm input,
                                               // thread-private in-place

  const int n4 = (Bn * 512) / 4;
  convert_bf16<<<(n4 + 255) / 256, 256, 0, stream>>>(state, stateB, n4);
  transpose_f32_bf16<<<dim3(32, 16), 256, 0, stream>>>(W1, W1T, 512, 1024, 1024);
  transpose_f32_bf16<<<dim3(32, 32), 256, 0, stream>>>(W2, W2T, 1024, 1024, 1024);
  transpose_f32_bf16<<<dim3(1, 32),  256, 0, stream>>>(W3, W3T, 1024, 24, 32);
  setup_admm<<<1, 256, 0, stream>>>(Aeq, beq, Ain, bin, ub, lb, cbuf, cbuf2);

  gemm_bt<128, 128, 2, 2, 4, 4, 0><<<dim3(8, Bn / 128), 256, 0, stream>>>(
      stateB, W1T, b1, H1, 512, 1024, 1024);
  gemm_bt<128, 128, 2, 2, 4, 4, 0><<<dim3(8, Bn / 128), 256, 0, stream>>>(
      H1, W2T, b2, H2, 1024, 1024, 1024);
  gemm_bt<64, 32, 4, 1, 1, 2, 1><<<dim3(1, Bn / 64), 256, 0, stream>>>(
      H2, W3T, b3, rawb, 1024, 24, 24);

  admm_kernel<<<Bn / 64, 64, 0, stream>>>(rawb, cbuf, cbuf2, (float*)d_out);
}

// Round 6
// 594.699 us; speedup vs baseline: 2.7305x; 1.3781x over previous
//
#include <hip/hip_runtime.h>

using uint = unsigned int;
using ushort = unsigned short;

typedef __attribute__((ext_vector_type(8))) short bf16x8;
typedef __attribute__((ext_vector_type(4))) float f32x4;

#define ADMM_ITERS 100
#define RHO_C 1.0f
#define SIGMA_C 1e-6f

__device__ inline ushort f2bf(float f) {
  union { float f; uint u; } c; c.f = f;
  uint u = c.u;
  uint r = (u + 0x7fffu + ((u >> 16) & 1u)) >> 16;
  return (ushort)r;
}

template<int PAT> __device__ inline float swzf(float x) {
  return __int_as_float(__builtin_amdgcn_ds_swizzle(__float_as_int(x), PAT));
}
#define SWZ1(x) swzf<0x041F>(x)   // lane ^ 1 (quad-local)
#define SWZ2(x) swzf<0x081F>(x)   // lane ^ 2 (quad-local)

// ---------------------------------------------------------------------------
// f32 -> bf16 elementwise convert (4 elems/thread, float4 loads)
// ---------------------------------------------------------------------------
__global__ void convert_bf16(const float* __restrict__ in, ushort* __restrict__ out, int n4) {
  int i = blockIdx.x * blockDim.x + threadIdx.x;
  if (i >= n4) return;
  float4 v = ((const float4*)in)[i];
  uint2 p;
  p.x = (uint)f2bf(v.x) | ((uint)f2bf(v.y) << 16);
  p.y = (uint)f2bf(v.z) | ((uint)f2bf(v.w) << 16);
  ((uint2*)out)[i] = p;
}

// ---------------------------------------------------------------------------
// f32 transpose -> bf16: out[c][r] = bf16(in[r][c]); rows c in [C,Cout) zeroed.
// ---------------------------------------------------------------------------
__global__ void transpose_f32_bf16(const float* __restrict__ in, ushort* __restrict__ out,
                                   int R, int C, int Cout) {
  __shared__ float t[32][33];
  const int c0 = blockIdx.x * 32, r0 = blockIdx.y * 32;
  const int tx = threadIdx.x & 31, ty = threadIdx.x >> 5;
  for (int rr = ty; rr < 32; rr += 8) {
    int r = r0 + rr, c = c0 + tx;
    float v = 0.0f;
    if (r < R && c < C) v = in[(long)r * C + c];
    t[rr][tx] = v;
  }
  __syncthreads();
  for (int rr = ty; rr < 32; rr += 8) {
    int c = c0 + rr, r = r0 + tx;
    if (c < Cout && r < R) out[(long)c * R + r] = f2bf(t[tx][rr]);
  }
}

// ---------------------------------------------------------------------------
// ADMM constants. cbuf layout (f32), total 1224:
//   Minv[576] @0 | A12[12x24] @576 | A12T[24x12] @864 |
//   lc[12] @1152 | uc[12] @1164 | lb[24] @1176 | ub[24] @1200
// Minv = inv((1+SIGMA+2*RHO)I + RHO*(Aeq^T Aeq + A^T A)) via Gauss-Jordan.
// ---------------------------------------------------------------------------
__global__ void setup_admm(const float* __restrict__ Aeq, const float* __restrict__ beq,
                           const float* __restrict__ A, const float* __restrict__ b,
                           const float* __restrict__ ub, const float* __restrict__ lb,
                           float* __restrict__ cbuf) {
  __shared__ float Aug[24][48];
  __shared__ float A12[12 * 24];
  __shared__ float fac[24];
  const int t = threadIdx.x;
  if (t < 96)  A12[t] = Aeq[t];          // rows 0-3
  if (t < 192) A12[96 + t] = A[t];       // rows 4-11
  __syncthreads();
  for (int idx = t; idx < 576; idx += 256) {
    int j = idx / 24, k = idx % 24;
    float s = (j == k) ? (1.0f + SIGMA_C + 2.0f * RHO_C) : 0.0f;
    for (int r = 0; r < 12; ++r) s += RHO_C * A12[r * 24 + j] * A12[r * 24 + k];
    Aug[j][k] = s;
    Aug[j][24 + k] = (j == k) ? 1.0f : 0.0f;
  }
  __syncthreads();
  for (int p = 0; p < 24; ++p) {
    float rp = 1.0f / Aug[p][p];
    if (t < 24) fac[t] = Aug[t][p];
    __syncthreads();
    if (t < 48) Aug[p][t] *= rp;
    __syncthreads();
    for (int idx = t; idx < 24 * 48; idx += 256) {
      int r = idx / 48, c = idx % 48;
      if (r != p) Aug[r][c] -= fac[r] * Aug[p][c];
    }
    __syncthreads();
  }
  for (int idx = t; idx < 576; idx += 256) cbuf[idx] = Aug[idx / 24][24 + idx % 24];
  for (int idx = t; idx < 288; idx += 256) cbuf[576 + idx] = A12[idx];
  for (int idx = t; idx < 288; idx += 256) {
    int j = idx / 12, r = idx % 12;
    cbuf[864 + idx] = A12[r * 24 + j];     // A12T[j][r]
  }
  if (t < 12) {
    float lv, uv;
    if (t < 4) { lv = beq[t]; uv = lv; }
    else       { lv = -INFINITY; uv = b[t - 4]; }
    cbuf[1152 + t] = lv;
    cbuf[1164 + t] = uv;
  }
  if (t < 24) {
    cbuf[1176 + t] = lb[t];
    cbuf[1200 + t] = ub[t];
  }
}

// ---------------------------------------------------------------------------
// bf16 GEMM, C = A[M,K] * Bt[N,K]^T (unchanged from round 5).
// ---------------------------------------------------------------------------
template<int BM, int BN, int WM, int WN, int TM, int TN, int MODE>
__global__ __launch_bounds__(256) void gemm_bt(
    const ushort* __restrict__ A, const ushort* __restrict__ Bt,
    const float* __restrict__ bias, void* __restrict__ Cout_,
    int K, int ldc, int nvalid) {
  constexpr int LDE = 40;
  __shared__ __align__(16) ushort lds[(BM + BN) * LDE];
  ushort* ldsA = lds;
  ushort* ldsB = lds + BM * LDE;

  const int tid = threadIdx.x;
  const int wave = tid >> 6;
  const int lane = tid & 63;
  const int blockM = blockIdx.y * BM;
  const int blockN = blockIdx.x * BN;
  const int wm = (wave / WN) * (TM * 16);
  const int wn = (wave % WN) * (TN * 16);

  f32x4 acc[TM][TN] = {};

  const int l15 = lane & 15;
  const int kq = lane >> 4;
  constexpr int CHUNKS = (BM + BN) * 4;

  for (int k0 = 0; k0 < K; k0 += 32) {
    for (int c = tid; c < CHUNKS; c += 256) {
      const int row = c >> 2, slot = c & 3;
      const ushort* src; int grow;
      if (row < BM) { src = A;  grow = blockM + row; }
      else          { src = Bt; grow = blockN + (row - BM); }
      bf16x8 v = *(const bf16x8*)(src + (long)grow * K + (k0 + slot * 8));
      *(bf16x8*)(lds + row * LDE + slot * 8) = v;
    }
    __syncthreads();

    bf16x8 af[TM], bfr[TN];
#pragma unroll
    for (int i = 0; i < TM; ++i)
      af[i] = *(const bf16x8*)(ldsA + (wm + i * 16 + l15) * LDE + kq * 8);
#pragma unroll
    for (int j = 0; j < TN; ++j)
      bfr[j] = *(const bf16x8*)(ldsB + (wn + j * 16 + l15) * LDE + kq * 8);
#pragma unroll
    for (int i = 0; i < TM; ++i)
#pragma unroll
      for (int j = 0; j < TN; ++j)
        acc[i][j] = __builtin_amdgcn_mfma_f32_16x16x32_bf16(af[i], bfr[j], acc[i][j], 0, 0, 0);
    __syncthreads();
  }

  const int ro = lane >> 4;
#pragma unroll
  for (int i = 0; i < TM; ++i) {
#pragma unroll
    for (int j = 0; j < TN; ++j) {
      const int col = blockN + wn + j * 16 + l15;
      float bv;
      if (MODE == 0) bv = bias[col];
      else bv = (col < nvalid) ? bias[col] : 0.0f;
#pragma unroll
      for (int r = 0; r < 4; ++r) {
        const int row = blockM + wm + i * 16 + ro * 4 + r;
        float v = acc[i][j][r] + bv;
        if (MODE == 0) {
          v = fmaxf(v, 0.0f);
          ((ushort*)Cout_)[(long)row * ldc + col] = f2bf(v);
        } else {
          if (col < nvalid) ((float*)Cout_)[(long)row * ldc + col] = v;
        }
      }
    }
  }
}

// ---------------------------------------------------------------------------
// ADMM, FOUR lanes per batch row (quad-split). Lane c = lane&3 owns
// x-indices j in {6c..6c+5} and constraint rows r in {3c..3c+2}.
// - per-lane state ~54 floats -> promotion/pressure safe at any VGPR budget
// - 1024 waves -> 4 waves/CU (every SIMD busy), vs round-5's 1 wave/CU
// - constants in LDS, TWO copies, base ping-pong 0<->1224 per iteration
//   (structurally defeats LICM; no inline asm -- round-4 post-mortem)
// - quad all-gather via ds_swizzle xor1/xor2 (45 swizzles/iter)
// Reads: <=4 distinct LDS addresses per instruction (16-way broadcast);
// worst-case 2-way bank aliasing (free per m136).
// I/-I mirror symmetry: 12 constraint + 24 box rows; rho=1.
// ---------------------------------------------------------------------------
__global__ __launch_bounds__(256) void admm_kernel(
    const float* raw, const float* __restrict__ cbuf, float* outp) {
  __shared__ float clds[2448];
  const int tid = threadIdx.x;
  for (int i = tid; i < 2448; i += 256) clds[i] = cbuf[i >= 1224 ? i - 1224 : i];
  __syncthreads();

  const int lane = tid & 63;
  const int c = lane & 3;
  const int row = blockIdx.x * 64 + (tid >> 6) * 16 + (lane >> 2);
  const int cm1 = c ^ 1, cm2 = c ^ 2, cm3 = c ^ 3;

  // per-lane bounds (owned slices), loaded once
  float lbv[6], ubv[6], lcb[3], ucb[3];
#pragma unroll
  for (int jj = 0; jj < 6; ++jj) {
    lbv[jj] = clds[1176 + 6 * c + jj];
    ubv[jj] = clds[1200 + 6 * c + jj];
  }
#pragma unroll
  for (int t = 0; t < 3; ++t) {
    lcb[t] = clds[1152 + 3 * c + t];
    ucb[t] = clds[1164 + 3 * c + t];
  }

  // q slice (owned j)
  float q[6];
  {
    const float2* rp = (const float2*)(raw + (long)row * 24 + 6 * c);
#pragma unroll
    for (int i = 0; i < 3; ++i) {
      float2 v = rp[i];
      q[2 * i] = v.x; q[2 * i + 1] = v.y;
    }
  }
  float X[6], Zb[6], Yb[6], Zc[3], Yc[3];
#pragma unroll
  for (int jj = 0; jj < 6; ++jj) { X[jj] = 0.0f; Zb[jj] = 0.0f; Yb[jj] = 0.0f; }
#pragma unroll
  for (int t = 0; t < 3; ++t) { Zc[t] = 0.0f; Yc[t] = 0.0f; }

  int off = 0;                               // LDS constant-copy ping-pong
#pragma unroll 1
  for (int it = 0; it < ADMM_ITERS; ++it) {
    const float* Mv   = clds + off;          // Minv[j*24+k]
    const float* A12p = clds + off + 576;    // A12[r*24+j]
    const float* A12T = clds + off + 864;    // A12T[j*12+r]

    // ---- phase A: rhs (owned j) ----
    float u[4][3];
#pragma unroll
    for (int t = 0; t < 3; ++t) u[0][t] = RHO_C * Zc[t] - Yc[t];
#pragma unroll
    for (int t = 0; t < 3; ++t) u[1][t] = SWZ1(u[0][t]);
#pragma unroll
    for (int t = 0; t < 3; ++t) u[2][t] = SWZ2(u[0][t]);
#pragma unroll
    for (int t = 0; t < 3; ++t) u[3][t] = SWZ2(u[1][t]);

    float rhs[6];
#pragma unroll
    for (int jj = 0; jj < 6; ++jj)
      rhs[jj] = q[jj] + SIGMA_C * X[jj] + 2.0f * (RHO_C * Zb[jj] - Yb[jj]);
    const int cms[4] = {c, cm1, cm2, cm3};
#pragma unroll
    for (int m = 0; m < 4; ++m) {
      const int rb = 3 * cms[m];
#pragma unroll
      for (int t = 0; t < 3; ++t)
#pragma unroll
        for (int jj = 0; jj < 6; ++jj)
          rhs[jj] += u[m][t] * A12T[(6 * c + jj) * 12 + rb + t];
    }

    // ---- phase B: X = Minv * rhs (owned j; all-gather rhs) ----
    float rr[4][6];
#pragma unroll
    for (int kk = 0; kk < 6; ++kk) rr[0][kk] = rhs[kk];
#pragma unroll
    for (int kk = 0; kk < 6; ++kk) rr[1][kk] = SWZ1(rr[0][kk]);
#pragma unroll
    for (int kk = 0; kk < 6; ++kk) rr[2][kk] = SWZ2(rr[0][kk]);
#pragma unroll
    for (int kk = 0; kk < 6; ++kk) rr[3][kk] = SWZ2(rr[1][kk]);
#pragma unroll
    for (int jj = 0; jj < 6; ++jj) {
      float s = 0.0f;
#pragma unroll
      for (int m = 0; m < 4; ++m) {
        const int kb = 6 * cms[m];
#pragma unroll
        for (int kk = 0; kk < 6; ++kk)
          s += rr[m][kk] * Mv[(6 * c + jj) * 24 + kb + kk];
      }
      X[jj] = s;
    }

    // ---- phase C: constraint rows (owned r; all-gather X) ----
    float xx[4][6];
#pragma unroll
    for (int kk = 0; kk < 6; ++kk) xx[0][kk] = X[kk];
#pragma unroll
    for (int kk = 0; kk < 6; ++kk) xx[1][kk] = SWZ1(xx[0][kk]);
#pragma unroll
    for (int kk = 0; kk < 6; ++kk) xx[2][kk] = SWZ2(xx[0][kk]);
#pragma unroll
    for (int kk = 0; kk < 6; ++kk) xx[3][kk] = SWZ2(xx[1][kk]);
#pragma unroll
    for (int tt = 0; tt < 3; ++tt) {
      float s = 0.0f;
#pragma unroll
      for (int m = 0; m < 4; ++m) {
        const int kb = 6 * cms[m];
#pragma unroll
        for (int kk = 0; kk < 6; ++kk)
          s += xx[m][kk] * A12p[(3 * c + tt) * 24 + kb + kk];
      }
      float zn = fminf(fmaxf(s + Yc[tt], lcb[tt]), ucb[tt]);   // rho = 1
      Yc[tt] += s - zn;
      Zc[tt] = zn;
    }
    // ---- box rows (owned j) ----
#pragma unroll
    for (int jj = 0; jj < 6; ++jj) {
      float s = X[jj];
      float zn = fminf(fmaxf(s + Yb[jj], lbv[jj]), ubv[jj]);
      Yb[jj] += s - zn;
      Zb[jj] = zn;
    }
    off = 1224 - off;                        // ping-pong constant copies
  }

  float2* op = (float2*)(outp + (long)row * 24 + 6 * c);
#pragma unroll
  for (int i = 0; i < 3; ++i)
    op[i] = make_float2(X[2 * i], X[2 * i + 1]);
}

// ---------------------------------------------------------------------------
extern "C" void kernel_launch(void* const* d_in, const int* in_sizes, int n_in,
                              void* d_out, int out_size, void* d_ws, size_t ws_size,
                              hipStream_t stream) {
  const float* state = (const float*)d_in[0];
  const float* Aeq   = (const float*)d_in[1];
  const float* beq   = (const float*)d_in[2];
  const float* Ain   = (const float*)d_in[3];
  const float* bin   = (const float*)d_in[4];
  const float* ub    = (const float*)d_in[5];
  const float* lb    = (const float*)d_in[6];
  const float* W1    = (const float*)d_in[7];
  const float* b1    = (const float*)d_in[8];
  const float* W2    = (const float*)d_in[9];
  const float* b2    = (const float*)d_in[10];
  const float* W3    = (const float*)d_in[11];
  const float* b3    = (const float*)d_in[12];

  const int Bn = in_sizes[0] / 512;            // 16384
  char* ws = (char*)d_ws;
  ushort* stateB = (ushort*)(ws + 0);          // 16384x512 bf16  (16 MB)
  ushort* W1T    = (ushort*)(ws + 16777216);   // 1024x512        (1 MB)
  ushort* W2T    = (ushort*)(ws + 17825792);   // 1024x1024       (2 MB)
  ushort* W3T    = (ushort*)(ws + 19922944);   // 32x1024 (rows>=24 zero)
  float*  cbuf   = (float*) (ws + 19988480);   // 1224 f32
  ushort* H1     = (ushort*)(ws + 21565440);   // 16384x1024 bf16 (32 MB)
  ushort* H2     = (ushort*)(ws + 55119872);   // 16384x1024 bf16 (32 MB)
  float*  rawb   = (float*)d_out;              // gemm3 out = admm in (in-place)

  const int n4 = (Bn * 512) / 4;
  convert_bf16<<<(n4 + 255) / 256, 256, 0, stream>>>(state, stateB, n4);
  transpose_f32_bf16<<<dim3(32, 16), 256, 0, stream>>>(W1, W1T, 512, 1024, 1024);
  transpose_f32_bf16<<<dim3(32, 32), 256, 0, stream>>>(W2, W2T, 1024, 1024, 1024);
  transpose_f32_bf16<<<dim3(1, 32),  256, 0, stream>>>(W3, W3T, 1024, 24, 32);
  setup_admm<<<1, 256, 0, stream>>>(Aeq, beq, Ain, bin, ub, lb, cbuf);

  gemm_bt<128, 128, 2, 2, 4, 4, 0><<<dim3(8, Bn / 128), 256, 0, stream>>>(
      stateB, W1T, b1, H1, 512, 1024, 1024);
  gemm_bt<128, 128, 2, 2, 4, 4, 0><<<dim3(8, Bn / 128), 256, 0, stream>>>(
      H1, W2T, b2, H2, 1024, 1024, 1024);
  gemm_bt<64, 32, 4, 1, 1, 2, 1><<<dim3(1, Bn / 64), 256, 0, stream>>>(
      H2, W3T, b3, rawb, 1024, 24, 24);

  admm_kernel<<<Bn / 64, 256, 0, stream>>>(rawb, cbuf, (float*)d_out);
}

// Round 7
// 395.674 us; speedup vs baseline: 4.1040x; 1.5030x over previous
//
#include <hip/hip_runtime.h>

using uint = unsigned int;
using ushort = unsigned short;

typedef __attribute__((ext_vector_type(8))) short bf16x8;
typedef __attribute__((ext_vector_type(4))) float f32x4;

#define ADMM_ITERS 100
#define RHO_C 1.0f
#define SIGMA_C 1e-6f

__device__ inline ushort f2bf(float f) {
  union { float f; uint u; } c; c.f = f;
  uint u = c.u;
  uint r = (u + 0x7fffu + ((u >> 16) & 1u)) >> 16;
  return (ushort)r;
}

// quad_perm DPP cross-lane: result[l] = src[l^1] / src[l^2]. VALU pipe, no LDS.
template<int CTRL> __device__ inline float movd(float x) {
  return __int_as_float(__builtin_amdgcn_mov_dpp(__float_as_int(x), CTRL, 0xf, 0xf, true));
}
#define DXOR1(x) movd<0xB1>(x)   // quad_perm [1,0,3,2]
#define DXOR2(x) movd<0x4E>(x)   // quad_perm [2,3,0,1]

// ---------------------------------------------------------------------------
// f32 -> bf16 elementwise convert (4 elems/thread, float4 loads)
// ---------------------------------------------------------------------------
__global__ void convert_bf16(const float* __restrict__ in, ushort* __restrict__ out, int n4) {
  int i = blockIdx.x * blockDim.x + threadIdx.x;
  if (i >= n4) return;
  float4 v = ((const float4*)in)[i];
  uint2 p;
  p.x = (uint)f2bf(v.x) | ((uint)f2bf(v.y) << 16);
  p.y = (uint)f2bf(v.z) | ((uint)f2bf(v.w) << 16);
  ((uint2*)out)[i] = p;
}

// ---------------------------------------------------------------------------
// f32 transpose -> bf16: out[c][r] = bf16(in[r][c]); rows c in [C,Cout) zeroed.
// ---------------------------------------------------------------------------
__global__ void transpose_f32_bf16(const float* __restrict__ in, ushort* __restrict__ out,
                                   int R, int C, int Cout) {
  __shared__ float t[32][33];
  const int c0 = blockIdx.x * 32, r0 = blockIdx.y * 32;
  const int tx = threadIdx.x & 31, ty = threadIdx.x >> 5;
  for (int rr = ty; rr < 32; rr += 8) {
    int r = r0 + rr, c = c0 + tx;
    float v = 0.0f;
    if (r < R && c < C) v = in[(long)r * C + c];
    t[rr][tx] = v;
  }
  __syncthreads();
  for (int rr = ty; rr < 32; rr += 8) {
    int c = c0 + rr, r = r0 + tx;
    if (c < Cout && r < R) out[(long)c * R + r] = f2bf(t[tx][rr]);
  }
}

// ---------------------------------------------------------------------------
// ADMM constants. cbuf layout (f32), total 1224:
//   Minv[24x24] @0 | A12[12x24] @576 | G = Minv*A12^T [24x12] @864 |
//   lc[12] @1152 | uc[12] @1164 | lb[24] @1176 | ub[24] @1200
// Minv = inv((1+SIGMA+2*RHO)I + RHO*(Aeq^T Aeq + A^T A)) via Gauss-Jordan.
// ---------------------------------------------------------------------------
__global__ void setup_admm(const float* __restrict__ Aeq, const float* __restrict__ beq,
                           const float* __restrict__ A, const float* __restrict__ b,
                           const float* __restrict__ ub, const float* __restrict__ lb,
                           float* __restrict__ cbuf) {
  __shared__ float Aug[24][48];
  __shared__ float A12[12 * 24];
  __shared__ float fac[24];
  const int t = threadIdx.x;
  if (t < 96)  A12[t] = Aeq[t];          // rows 0-3
  if (t < 192) A12[96 + t] = A[t];       // rows 4-11
  __syncthreads();
  for (int idx = t; idx < 576; idx += 256) {
    int j = idx / 24, k = idx % 24;
    float s = (j == k) ? (1.0f + SIGMA_C + 2.0f * RHO_C) : 0.0f;
    for (int r = 0; r < 12; ++r) s += RHO_C * A12[r * 24 + j] * A12[r * 24 + k];
    Aug[j][k] = s;
    Aug[j][24 + k] = (j == k) ? 1.0f : 0.0f;
  }
  __syncthreads();
  for (int p = 0; p < 24; ++p) {
    float rp = 1.0f / Aug[p][p];
    if (t < 24) fac[t] = Aug[t][p];
    __syncthreads();
    if (t < 48) Aug[p][t] *= rp;
    __syncthreads();
    for (int idx = t; idx < 24 * 48; idx += 256) {
      int r = idx / 48, c = idx % 48;
      if (r != p) Aug[r][c] -= fac[r] * Aug[p][c];
    }
    __syncthreads();
  }
  for (int idx = t; idx < 576; idx += 256) cbuf[idx] = Aug[idx / 24][24 + idx % 24];
  for (int idx = t; idx < 288; idx += 256) cbuf[576 + idx] = A12[idx];
  // G[j][r] = sum_k Minv[j][k] * A12[r][k]
  for (int idx = t; idx < 288; idx += 256) {
    int j = idx / 12, r = idx % 12;
    float s = 0.0f;
    for (int k = 0; k < 24; ++k) s += Aug[j][24 + k] * A12[r * 24 + k];
    cbuf[864 + idx] = s;
  }
  if (t < 12) {
    float lv, uv;
    if (t < 4) { lv = beq[t]; uv = lv; }
    else       { lv = -INFINITY; uv = b[t - 4]; }
    cbuf[1152 + t] = lv;
    cbuf[1164 + t] = uv;
  }
  if (t < 24) {
    cbuf[1176 + t] = lb[t];
    cbuf[1200 + t] = ub[t];
  }
}

// ---------------------------------------------------------------------------
// bf16 GEMM, C = A[M,K] * Bt[N,K]^T (unchanged from round 6 — known good).
// ---------------------------------------------------------------------------
template<int BM, int BN, int WM, int WN, int TM, int TN, int MODE>
__global__ __launch_bounds__(256) void gemm_bt(
    const ushort* __restrict__ A, const ushort* __restrict__ Bt,
    const float* __restrict__ bias, void* __restrict__ Cout_,
    int K, int ldc, int nvalid) {
  constexpr int LDE = 40;
  __shared__ __align__(16) ushort lds[(BM + BN) * LDE];
  ushort* ldsA = lds;
  ushort* ldsB = lds + BM * LDE;

  const int tid = threadIdx.x;
  const int wave = tid >> 6;
  const int lane = tid & 63;
  const int blockM = blockIdx.y * BM;
  const int blockN = blockIdx.x * BN;
  const int wm = (wave / WN) * (TM * 16);
  const int wn = (wave % WN) * (TN * 16);

  f32x4 acc[TM][TN] = {};

  const int l15 = lane & 15;
  const int kq = lane >> 4;
  constexpr int CHUNKS = (BM + BN) * 4;

  for (int k0 = 0; k0 < K; k0 += 32) {
    for (int c = tid; c < CHUNKS; c += 256) {
      const int row = c >> 2, slot = c & 3;
      const ushort* src; int grow;
      if (row < BM) { src = A;  grow = blockM + row; }
      else          { src = Bt; grow = blockN + (row - BM); }
      bf16x8 v = *(const bf16x8*)(src + (long)grow * K + (k0 + slot * 8));
      *(bf16x8*)(lds + row * LDE + slot * 8) = v;
    }
    __syncthreads();

    bf16x8 af[TM], bfr[TN];
#pragma unroll
    for (int i = 0; i < TM; ++i)
      af[i] = *(const bf16x8*)(ldsA + (wm + i * 16 + l15) * LDE + kq * 8);
#pragma unroll
    for (int j = 0; j < TN; ++j)
      bfr[j] = *(const bf16x8*)(ldsB + (wn + j * 16 + l15) * LDE + kq * 8);
#pragma unroll
    for (int i = 0; i < TM; ++i)
#pragma unroll
      for (int j = 0; j < TN; ++j)
        acc[i][j] = __builtin_amdgcn_mfma_f32_16x16x32_bf16(af[i], bfr[j], acc[i][j], 0, 0, 0);
    __syncthreads();
  }

  const int ro = lane >> 4;
#pragma unroll
  for (int i = 0; i < TM; ++i) {
#pragma unroll
    for (int j = 0; j < TN; ++j) {
      const int col = blockN + wn + j * 16 + l15;
      float bv;
      if (MODE == 0) bv = bias[col];
      else bv = (col < nvalid) ? bias[col] : 0.0f;
#pragma unroll
      for (int r = 0; r < 4; ++r) {
        const int row = blockM + wm + i * 16 + ro * 4 + r;
        float v = acc[i][j][r] + bv;
        if (MODE == 0) {
          v = fmaxf(v, 0.0f);
          ((ushort*)Cout_)[(long)row * ldc + col] = f2bf(v);
        } else {
          if (col < nvalid) ((float*)Cout_)[(long)row * ldc + col] = v;
        }
      }
    }
  }
}

// ---------------------------------------------------------------------------
// ADMM, 4 lanes/row, ALL constants register-resident, zero memory ops in loop.
// - __launch_bounds__(256,1): 1 wave/EU -> ~512-VGPR budget (grid only gives
//   4 waves/CU anyway, so no occupancy loss). Round-6 counters: VGPR=68 +
//   117 LDS ops/iter = lgkm-stall-bound. Here the loop is pure VALU + DPP.
// - Quad permutation baked into the constant LOAD addresses (cMp[jj][m][kk] =
//   Minv[6c+jj][6(c^m)+kk]) so all register-array indices are static.
// - Cross-lane all-gather via v_mov_b32 dpp quad_perm (VALU pipe, no lgkmcnt).
// - w-formulation (w = Zt + Y): per-row state = w only; sigma*X dropped
//   (|effect| ~1e-5 << 0.02 threshold). Iter 1 peeled (Z0=Y0=0).
// - I/-I mirror: box rows contribute 2*u_b (u from -I rows = -u_b).
// ---------------------------------------------------------------------------
__global__ __launch_bounds__(256, 1) void admm_kernel(
    const float* raw, const float* __restrict__ cbuf, float* outp) {
  const int tid = threadIdx.x;
  const int lane = tid & 63;
  const int c = lane & 3;
  const int row = blockIdx.x * 64 + (tid >> 6) * 16 + (lane >> 2);

  // ---- load permuted constants into registers (static indices thereafter) --
  float cMp[6][4][6];   // Minv[6c+jj][6(c^m)+kk]
  float cGp[6][4][3];   // G[6c+jj][3(c^m)+tt]
  float cAp[3][4][6];   // A12[3c+tt][6(c^m)+kk]
#pragma unroll
  for (int jj = 0; jj < 6; ++jj)
#pragma unroll
    for (int m = 0; m < 4; ++m) {
      const float2* p = (const float2*)(cbuf + (6 * c + jj) * 24 + 6 * (c ^ m));
#pragma unroll
      for (int h = 0; h < 3; ++h) {
        float2 v = p[h];
        cMp[jj][m][2 * h] = v.x; cMp[jj][m][2 * h + 1] = v.y;
      }
      const float* g = cbuf + 864 + (6 * c + jj) * 12 + 3 * (c ^ m);
#pragma unroll
      for (int h = 0; h < 3; ++h) cGp[jj][m][h] = g[h];
    }
#pragma unroll
  for (int tt = 0; tt < 3; ++tt)
#pragma unroll
    for (int m = 0; m < 4; ++m) {
      const float2* p = (const float2*)(cbuf + 576 + (3 * c + tt) * 24 + 6 * (c ^ m));
#pragma unroll
      for (int h = 0; h < 3; ++h) {
        float2 v = p[h];
        cAp[tt][m][2 * h] = v.x; cAp[tt][m][2 * h + 1] = v.y;
      }
    }
  float lbv[6], ubv[6], lcb[3], ucb[3];
#pragma unroll
  for (int jj = 0; jj < 6; ++jj) {
    lbv[jj] = cbuf[1176 + 6 * c + jj];
    ubv[jj] = cbuf[1200 + 6 * c + jj];
  }
#pragma unroll
  for (int tt = 0; tt < 3; ++tt) {
    lcb[tt] = cbuf[1152 + 3 * c + tt];
    ucb[tt] = cbuf[1164 + 3 * c + tt];
  }

  // ---- q slice + iteration-1 peel: X1 = Minv*raw, w1 = A*X1 ---------------
  float qv[6];
  {
    const float2* rp = (const float2*)(raw + (long)row * 24 + 6 * c);
#pragma unroll
    for (int i = 0; i < 3; ++i) { float2 v = rp[i]; qv[2 * i] = v.x; qv[2 * i + 1] = v.y; }
  }
  float ga[4][6];
#pragma unroll
  for (int k = 0; k < 6; ++k) ga[0][k] = qv[k];
#pragma unroll
  for (int k = 0; k < 6; ++k) ga[1][k] = DXOR1(ga[0][k]);
#pragma unroll
  for (int k = 0; k < 6; ++k) ga[2][k] = DXOR2(ga[0][k]);
#pragma unroll
  for (int k = 0; k < 6; ++k) ga[3][k] = DXOR2(ga[1][k]);

  float qM[6], X[6], wb[6], wc[3];
#pragma unroll
  for (int jj = 0; jj < 6; ++jj) {
    float s = 0.0f;
#pragma unroll
    for (int m = 0; m < 4; ++m)
#pragma unroll
      for (int k = 0; k < 6; ++k) s += cMp[jj][m][k] * ga[m][k];
    qM[jj] = s; X[jj] = s; wb[jj] = s;
  }
#pragma unroll
  for (int k = 0; k < 6; ++k) ga[0][k] = X[k];
#pragma unroll
  for (int k = 0; k < 6; ++k) ga[1][k] = DXOR1(ga[0][k]);
#pragma unroll
  for (int k = 0; k < 6; ++k) ga[2][k] = DXOR2(ga[0][k]);
#pragma unroll
  for (int k = 0; k < 6; ++k) ga[3][k] = DXOR2(ga[1][k]);
#pragma unroll
  for (int tt = 0; tt < 3; ++tt) {
    float s = 0.0f;
#pragma unroll
    for (int m = 0; m < 4; ++m)
#pragma unroll
      for (int k = 0; k < 6; ++k) s += cAp[tt][m][k] * ga[m][k];
    wc[tt] = s;
  }

  // ---- 99 remaining iterations: pure VALU + DPP ---------------------------
#pragma unroll 1
  for (int it = 1; it < ADMM_ITERS; ++it) {
    float Zb[6], Zc[3], ub2[6], ucv[3];
#pragma unroll
    for (int jj = 0; jj < 6; ++jj) {
      Zb[jj] = fminf(fmaxf(wb[jj], lbv[jj]), ubv[jj]);
      ub2[jj] = 2.0f * (2.0f * Zb[jj] - wb[jj]);          // 2*u_b (mirror x2)
    }
#pragma unroll
    for (int tt = 0; tt < 3; ++tt) {
      Zc[tt] = fminf(fmaxf(wc[tt], lcb[tt]), ucb[tt]);
      ucv[tt] = 2.0f * Zc[tt] - wc[tt];                   // u_c
    }
    float ua[4][6], uca[4][3];
#pragma unroll
    for (int k = 0; k < 6; ++k) ua[0][k] = ub2[k];
#pragma unroll
    for (int k = 0; k < 6; ++k) ua[1][k] = DXOR1(ua[0][k]);
#pragma unroll
    for (int k = 0; k < 6; ++k) ua[2][k] = DXOR2(ua[0][k]);
#pragma unroll
    for (int k = 0; k < 6; ++k) ua[3][k] = DXOR2(ua[1][k]);
#pragma unroll
    for (int k = 0; k < 3; ++k) uca[0][k] = ucv[k];
#pragma unroll
    for (int k = 0; k < 3; ++k) uca[1][k] = DXOR1(uca[0][k]);
#pragma unroll
    for (int k = 0; k < 3; ++k) uca[2][k] = DXOR2(uca[0][k]);
#pragma unroll
    for (int k = 0; k < 3; ++k) uca[3][k] = DXOR2(uca[1][k]);

    // X = qM + Minv*(2u_b) + G*u_c
#pragma unroll
    for (int jj = 0; jj < 6; ++jj) {
      float s = qM[jj];
#pragma unroll
      for (int m = 0; m < 4; ++m) {
#pragma unroll
        for (int k = 0; k < 6; ++k) s += cMp[jj][m][k] * ua[m][k];
#pragma unroll
        for (int k = 0; k < 3; ++k) s += cGp[jj][m][k] * uca[m][k];
      }
      X[jj] = s;
      wb[jj] = s + (wb[jj] - Zb[jj]);                     // w_b' = X + Y_b
    }
    // w_c' = A12*X + (w_c - Z_c)
    float xa[4][6];
#pragma unroll
    for (int k = 0; k < 6; ++k) xa[0][k] = X[k];
#pragma unroll
    for (int k = 0; k < 6; ++k) xa[1][k] = DXOR1(xa[0][k]);
#pragma unroll
    for (int k = 0; k < 6; ++k) xa[2][k] = DXOR2(xa[0][k]);
#pragma unroll
    for (int k = 0; k < 6; ++k) xa[3][k] = DXOR2(xa[1][k]);
#pragma unroll
    for (int tt = 0; tt < 3; ++tt) {
      float s = wc[tt] - Zc[tt];
#pragma unroll
      for (int m = 0; m < 4; ++m)
#pragma unroll
        for (int k = 0; k < 6; ++k) s += cAp[tt][m][k] * xa[m][k];
      wc[tt] = s;
    }
  }

  float2* op = (float2*)(outp + (long)row * 24 + 6 * c);
#pragma unroll
  for (int i = 0; i < 3; ++i)
    op[i] = make_float2(X[2 * i], X[2 * i + 1]);
}

// ---------------------------------------------------------------------------
extern "C" void kernel_launch(void* const* d_in, const int* in_sizes, int n_in,
                              void* d_out, int out_size, void* d_ws, size_t ws_size,
                              hipStream_t stream) {
  const float* state = (const float*)d_in[0];
  const float* Aeq   = (const float*)d_in[1];
  const float* beq   = (const float*)d_in[2];
  const float* Ain   = (const float*)d_in[3];
  const float* bin   = (const float*)d_in[4];
  const float* ub    = (const float*)d_in[5];
  const float* lb    = (const float*)d_in[6];
  const float* W1    = (const float*)d_in[7];
  const float* b1    = (const float*)d_in[8];
  const float* W2    = (const float*)d_in[9];
  const float* b2    = (const float*)d_in[10];
  const float* W3    = (const float*)d_in[11];
  const float* b3    = (const float*)d_in[12];

  const int Bn = in_sizes[0] / 512;            // 16384
  char* ws = (char*)d_ws;
  ushort* stateB = (ushort*)(ws + 0);          // 16384x512 bf16  (16 MB)
  ushort* W1T    = (ushort*)(ws + 16777216);   // 1024x512        (1 MB)
  ushort* W2T    = (ushort*)(ws + 17825792);   // 1024x1024       (2 MB)
  ushort* W3T    = (ushort*)(ws + 19922944);   // 32x1024 (rows>=24 zero)
  float*  cbuf   = (float*) (ws + 19988480);   // 1224 f32
  ushort* H1     = (ushort*)(ws + 21565440);   // 16384x1024 bf16 (32 MB)
  ushort* H2     = (ushort*)(ws + 55119872);   // 16384x1024 bf16 (32 MB)
  float*  rawb   = (float*)d_out;              // gemm3 out = admm in (in-place)

  const int n4 = (Bn * 512) / 4;
  convert_bf16<<<(n4 + 255) / 256, 256, 0, stream>>>(state, stateB, n4);
  transpose_f32_bf16<<<dim3(32, 16), 256, 0, stream>>>(W1, W1T, 512, 1024, 1024);
  transpose_f32_bf16<<<dim3(32, 32), 256, 0, stream>>>(W2, W2T, 1024, 1024, 1024);
  transpose_f32_bf16<<<dim3(1, 32),  256, 0, stream>>>(W3, W3T, 1024, 24, 32);
  setup_admm<<<1, 256, 0, stream>>>(Aeq, beq, Ain, bin, ub, lb, cbuf);

  gemm_bt<128, 128, 2, 2, 4, 4, 0><<<dim3(8, Bn / 128), 256, 0, stream>>>(
      stateB, W1T, b1, H1, 512, 1024, 1024);
  gemm_bt<128, 128, 2, 2, 4, 4, 0><<<dim3(8, Bn / 128), 256, 0, stream>>>(
      H1, W2T, b2, H2, 1024, 1024, 1024);
  gemm_bt<64, 32, 4, 1, 1, 2, 1><<<dim3(1, Bn / 64), 256, 0, stream>>>(
      H2, W3T, b3, rawb, 1024, 24, 24);

  admm_kernel<<<Bn / 64, 256, 0, stream>>>(rawb, cbuf, (float*)d_out);
}

// Round 8
// 332.372 us; speedup vs baseline: 4.8856x; 1.1905x over previous
//
#include <hip/hip_runtime.h>

using uint = unsigned int;
using ushort = unsigned short;

typedef __attribute__((ext_vector_type(8))) short bf16x8;
typedef __attribute__((ext_vector_type(4))) float f32x4;

#define ADMM_ITERS 100
#define RHO_C 1.0f
#define SIGMA_C 1e-6f

__device__ inline ushort f2bf(float f) {
  union { float f; uint u; } c; c.f = f;
  uint u = c.u;
  uint r = (u + 0x7fffu + ((u >> 16) & 1u)) >> 16;
  return (ushort)r;
}

// quad_perm DPP cross-lane: result[l] = src[l^1] / src[l^2]. VALU pipe, no LDS.
template<int CTRL> __device__ inline float movd(float x) {
  return __int_as_float(__builtin_amdgcn_mov_dpp(__float_as_int(x), CTRL, 0xf, 0xf, true));
}
#define DXOR1(x) movd<0xB1>(x)   // quad_perm [1,0,3,2]
#define DXOR2(x) movd<0x4E>(x)   // quad_perm [2,3,0,1]

__device__ inline void gload_lds16(const void* g, void* l) {
  __builtin_amdgcn_global_load_lds(
      (const __attribute__((address_space(1))) void*)g,
      (__attribute__((address_space(3))) void*)l, 16, 0, 0);
}

// ---------------------------------------------------------------------------
// f32 -> bf16 elementwise convert (4 elems/thread, float4 loads)
// ---------------------------------------------------------------------------
__global__ void convert_bf16(const float* __restrict__ in, ushort* __restrict__ out, int n4) {
  int i = blockIdx.x * blockDim.x + threadIdx.x;
  if (i >= n4) return;
  float4 v = ((const float4*)in)[i];
  uint2 p;
  p.x = (uint)f2bf(v.x) | ((uint)f2bf(v.y) << 16);
  p.y = (uint)f2bf(v.z) | ((uint)f2bf(v.w) << 16);
  ((uint2*)out)[i] = p;
}

// ---------------------------------------------------------------------------
// f32 transpose -> bf16: out[c][r] = bf16(in[r][c]); rows c in [C,Cout) zeroed.
// ---------------------------------------------------------------------------
__global__ void transpose_f32_bf16(const float* __restrict__ in, ushort* __restrict__ out,
                                   int R, int C, int Cout) {
  __shared__ float t[32][33];
  const int c0 = blockIdx.x * 32, r0 = blockIdx.y * 32;
  const int tx = threadIdx.x & 31, ty = threadIdx.x >> 5;
  for (int rr = ty; rr < 32; rr += 8) {
    int r = r0 + rr, c = c0 + tx;
    float v = 0.0f;
    if (r < R && c < C) v = in[(long)r * C + c];
    t[rr][tx] = v;
  }
  __syncthreads();
  for (int rr = ty; rr < 32; rr += 8) {
    int c = c0 + rr, r = r0 + tx;
    if (c < Cout && r < R) out[(long)c * R + r] = f2bf(t[tx][rr]);
  }
}

// ---------------------------------------------------------------------------
// ADMM constants. cbuf layout (f32), total 1224:
//   Minv[24x24] @0 | A12[12x24] @576 | G = Minv*A12^T [24x12] @864 |
//   lc[12] @1152 | uc[12] @1164 | lb[24] @1176 | ub[24] @1200
// Minv = inv((1+SIGMA+2*RHO)I + RHO*(Aeq^T Aeq + A^T A)) via Gauss-Jordan.
// ---------------------------------------------------------------------------
__global__ void setup_admm(const float* __restrict__ Aeq, const float* __restrict__ beq,
                           const float* __restrict__ A, const float* __restrict__ b,
                           const float* __restrict__ ub, const float* __restrict__ lb,
                           float* __restrict__ cbuf) {
  __shared__ float Aug[24][48];
  __shared__ float A12[12 * 24];
  __shared__ float fac[24];
  const int t = threadIdx.x;
  if (t < 96)  A12[t] = Aeq[t];          // rows 0-3
  if (t < 192) A12[96 + t] = A[t];       // rows 4-11
  __syncthreads();
  for (int idx = t; idx < 576; idx += 256) {
    int j = idx / 24, k = idx % 24;
    float s = (j == k) ? (1.0f + SIGMA_C + 2.0f * RHO_C) : 0.0f;
    for (int r = 0; r < 12; ++r) s += RHO_C * A12[r * 24 + j] * A12[r * 24 + k];
    Aug[j][k] = s;
    Aug[j][24 + k] = (j == k) ? 1.0f : 0.0f;
  }
  __syncthreads();
  for (int p = 0; p < 24; ++p) {
    float rp = 1.0f / Aug[p][p];
    if (t < 24) fac[t] = Aug[t][p];
    __syncthreads();
    if (t < 48) Aug[p][t] *= rp;
    __syncthreads();
    for (int idx = t; idx < 24 * 48; idx += 256) {
      int r = idx / 48, c = idx % 48;
      if (r != p) Aug[r][c] -= fac[r] * Aug[p][c];
    }
    __syncthreads();
  }
  for (int idx = t; idx < 576; idx += 256) cbuf[idx] = Aug[idx / 24][24 + idx % 24];
  for (int idx = t; idx < 288; idx += 256) cbuf[576 + idx] = A12[idx];
  // G[j][r] = sum_k Minv[j][k] * A12[r][k]
  for (int idx = t; idx < 288; idx += 256) {
    int j = idx / 12, r = idx % 12;
    float s = 0.0f;
    for (int k = 0; k < 24; ++k) s += Aug[j][24 + k] * A12[r * 24 + k];
    cbuf[864 + idx] = s;
  }
  if (t < 12) {
    float lv, uv;
    if (t < 4) { lv = beq[t]; uv = lv; }
    else       { lv = -INFINITY; uv = b[t - 4]; }
    cbuf[1152 + t] = lv;
    cbuf[1164 + t] = uv;
  }
  if (t < 24) {
    cbuf[1176 + t] = lb[t];
    cbuf[1200 + t] = ub[t];
  }
}

// ---------------------------------------------------------------------------
// bf16 GEMM, C = A[M,K] * Bt[N,K]^T — m97-style staging:
//   global_load_lds width=16 (DMA, no VALU round-trip, no LDS writes)
//   XOR chunk swizzle baked into GLOBAL addresses: LDS[r*64 + ch*16] holds
//   global chunk (ch ^ ((r>>1)&3)) -> fragment ds_read_b128 spreads exactly
//   8 dwords/bank (wave64 floor, zero conflict cycles).
// Round-7 counters motivating this: MfmaUtil 12.6%, VALUBusy 22%,
// SQ_LDS_BANK_CONFLICT 8.4M with register staging + LDE=40 padding.
// MODE 0: C bf16 +bias relu.  MODE 1: C f32 +bias, cols < nvalid only.
// block 256 (4 waves), grid (N/BN, M/BM)
// ---------------------------------------------------------------------------
template<int BM, int BN, int WM, int WN, int TM, int TN, int MODE>
__global__ __launch_bounds__(256) void gemm_bt(
    const ushort* __restrict__ A, const ushort* __restrict__ Bt,
    const float* __restrict__ bias, void* __restrict__ Cout_,
    int K, int ldc, int nvalid) {
  __shared__ char lds[(BM + BN) * 64];
  char* ldsA = lds;
  char* ldsB = lds + BM * 64;

  const int tid = threadIdx.x;
  const int wave = tid >> 6;
  const int lane = tid & 63;
  const int blockM = blockIdx.y * BM;
  const int blockN = blockIdx.x * BN;
  const int wm = (wave / WN) * (TM * 16);
  const int wn = (wave % WN) * (TN * 16);

  f32x4 acc[TM][TN] = {};

  const int l15 = lane & 15;
  const int kq = lane >> 4;
  constexpr int AI = BM / 16;                 // A 16-row groups
  constexpr int TOT = (BM + BN) / 16;         // total 16-row groups
  const int srow = lane >> 2;                 // row within group (0..15)
  const int kb = (lane & 3) ^ ((srow >> 1) & 3);   // swizzled global chunk

  for (int k0 = 0; k0 < K; k0 += 32) {
    for (int inst = wave; inst < TOT; inst += 4) {
      const bool isA = inst < AI;
      const int i = isA ? inst : inst - AI;
      const ushort* gp = (isA ? A : Bt)
          + (long)((isA ? blockM : blockN) + i * 16 + srow) * K + (k0 + kb * 8);
      char* lp = (isA ? ldsA : ldsB) + i * 1024;   // wave-uniform base
      gload_lds16(gp, lp);
    }
    __syncthreads();

    bf16x8 af[TM], bfr[TN];
#pragma unroll
    for (int i = 0; i < TM; ++i) {
      int r = wm + i * 16 + l15;
      int ch = kq ^ ((r >> 1) & 3);
      af[i] = *(const bf16x8*)(ldsA + r * 64 + ch * 16);
    }
#pragma unroll
    for (int j = 0; j < TN; ++j) {
      int r = wn + j * 16 + l15;
      int ch = kq ^ ((r >> 1) & 3);
      bfr[j] = *(const bf16x8*)(ldsB + r * 64 + ch * 16);
    }
#pragma unroll
    for (int i = 0; i < TM; ++i)
#pragma unroll
      for (int j = 0; j < TN; ++j)
        acc[i][j] = __builtin_amdgcn_mfma_f32_16x16x32_bf16(af[i], bfr[j], acc[i][j], 0, 0, 0);
    __syncthreads();
  }

  const int ro = lane >> 4;
#pragma unroll
  for (int i = 0; i < TM; ++i) {
#pragma unroll
    for (int j = 0; j < TN; ++j) {
      const int col = blockN + wn + j * 16 + l15;
      float bv;
      if (MODE == 0) bv = bias[col];
      else bv = (col < nvalid) ? bias[col] : 0.0f;
#pragma unroll
      for (int r = 0; r < 4; ++r) {
        const int row = blockM + wm + i * 16 + ro * 4 + r;
        float v = acc[i][j][r] + bv;
        if (MODE == 0) {
          v = fmaxf(v, 0.0f);
          ((ushort*)Cout_)[(long)row * ldc + col] = f2bf(v);
        } else {
          if (col < nvalid) ((float*)Cout_)[(long)row * ldc + col] = v;
        }
      }
    }
  }
}

// ---------------------------------------------------------------------------
// ADMM, 4 lanes/row, all constants register-resident, zero memory ops in the
// loop (round-6 post-mortem). DPP quad_perm all-gathers; w-formulation.
// ---------------------------------------------------------------------------
__global__ __launch_bounds__(256, 1) void admm_kernel(
    const float* raw, const float* __restrict__ cbuf, float* outp) {
  const int tid = threadIdx.x;
  const int lane = tid & 63;
  const int c = lane & 3;
  const int row = blockIdx.x * 64 + (tid >> 6) * 16 + (lane >> 2);

  float cMp[6][4][6];   // Minv[6c+jj][6(c^m)+kk]
  float cGp[6][4][3];   // G[6c+jj][3(c^m)+tt]
  float cAp[3][4][6];   // A12[3c+tt][6(c^m)+kk]
#pragma unroll
  for (int jj = 0; jj < 6; ++jj)
#pragma unroll
    for (int m = 0; m < 4; ++m) {
      const float2* p = (const float2*)(cbuf + (6 * c + jj) * 24 + 6 * (c ^ m));
#pragma unroll
      for (int h = 0; h < 3; ++h) {
        float2 v = p[h];
        cMp[jj][m][2 * h] = v.x; cMp[jj][m][2 * h + 1] = v.y;
      }
      const float* g = cbuf + 864 + (6 * c + jj) * 12 + 3 * (c ^ m);
#pragma unroll
      for (int h = 0; h < 3; ++h) cGp[jj][m][h] = g[h];
    }
#pragma unroll
  for (int tt = 0; tt < 3; ++tt)
#pragma unroll
    for (int m = 0; m < 4; ++m) {
      const float2* p = (const float2*)(cbuf + 576 + (3 * c + tt) * 24 + 6 * (c ^ m));
#pragma unroll
      for (int h = 0; h < 3; ++h) {
        float2 v = p[h];
        cAp[tt][m][2 * h] = v.x; cAp[tt][m][2 * h + 1] = v.y;
      }
    }
  float lbv[6], ubv[6], lcb[3], ucb[3];
#pragma unroll
  for (int jj = 0; jj < 6; ++jj) {
    lbv[jj] = cbuf[1176 + 6 * c + jj];
    ubv[jj] = cbuf[1200 + 6 * c + jj];
  }
#pragma unroll
  for (int tt = 0; tt < 3; ++tt) {
    lcb[tt] = cbuf[1152 + 3 * c + tt];
    ucb[tt] = cbuf[1164 + 3 * c + tt];
  }

  float qv[6];
  {
    const float2* rp = (const float2*)(raw + (long)row * 24 + 6 * c);
#pragma unroll
    for (int i = 0; i < 3; ++i) { float2 v = rp[i]; qv[2 * i] = v.x; qv[2 * i + 1] = v.y; }
  }
  float ga[4][6];
#pragma unroll
  for (int k = 0; k < 6; ++k) ga[0][k] = qv[k];
#pragma unroll
  for (int k = 0; k < 6; ++k) ga[1][k] = DXOR1(ga[0][k]);
#pragma unroll
  for (int k = 0; k < 6; ++k) ga[2][k] = DXOR2(ga[0][k]);
#pragma unroll
  for (int k = 0; k < 6; ++k) ga[3][k] = DXOR2(ga[1][k]);

  float qM[6], X[6], wb[6], wc[3];
#pragma unroll
  for (int jj = 0; jj < 6; ++jj) {
    float s = 0.0f;
#pragma unroll
    for (int m = 0; m < 4; ++m)
#pragma unroll
      for (int k = 0; k < 6; ++k) s += cMp[jj][m][k] * ga[m][k];
    qM[jj] = s; X[jj] = s; wb[jj] = s;
  }
#pragma unroll
  for (int k = 0; k < 6; ++k) ga[0][k] = X[k];
#pragma unroll
  for (int k = 0; k < 6; ++k) ga[1][k] = DXOR1(ga[0][k]);
#pragma unroll
  for (int k = 0; k < 6; ++k) ga[2][k] = DXOR2(ga[0][k]);
#pragma unroll
  for (int k = 0; k < 6; ++k) ga[3][k] = DXOR2(ga[1][k]);
#pragma unroll
  for (int tt = 0; tt < 3; ++tt) {
    float s = 0.0f;
#pragma unroll
    for (int m = 0; m < 4; ++m)
#pragma unroll
      for (int k = 0; k < 6; ++k) s += cAp[tt][m][k] * ga[m][k];
    wc[tt] = s;
  }

#pragma unroll 1
  for (int it = 1; it < ADMM_ITERS; ++it) {
    float Zb[6], Zc[3], ub2[6], ucv[3];
#pragma unroll
    for (int jj = 0; jj < 6; ++jj) {
      Zb[jj] = fminf(fmaxf(wb[jj], lbv[jj]), ubv[jj]);
      ub2[jj] = 2.0f * (2.0f * Zb[jj] - wb[jj]);
    }
#pragma unroll
    for (int tt = 0; tt < 3; ++tt) {
      Zc[tt] = fminf(fmaxf(wc[tt], lcb[tt]), ucb[tt]);
      ucv[tt] = 2.0f * Zc[tt] - wc[tt];
    }
    float ua[4][6], uca[4][3];
#pragma unroll
    for (int k = 0; k < 6; ++k) ua[0][k] = ub2[k];
#pragma unroll
    for (int k = 0; k < 6; ++k) ua[1][k] = DXOR1(ua[0][k]);
#pragma unroll
    for (int k = 0; k < 6; ++k) ua[2][k] = DXOR2(ua[0][k]);
#pragma unroll
    for (int k = 0; k < 6; ++k) ua[3][k] = DXOR2(ua[1][k]);
#pragma unroll
    for (int k = 0; k < 3; ++k) uca[0][k] = ucv[k];
#pragma unroll
    for (int k = 0; k < 3; ++k) uca[1][k] = DXOR1(uca[0][k]);
#pragma unroll
    for (int k = 0; k < 3; ++k) uca[2][k] = DXOR2(uca[0][k]);
#pragma unroll
    for (int k = 0; k < 3; ++k) uca[3][k] = DXOR2(uca[1][k]);

#pragma unroll
    for (int jj = 0; jj < 6; ++jj) {
      float s = qM[jj];
#pragma unroll
      for (int m = 0; m < 4; ++m) {
#pragma unroll
        for (int k = 0; k < 6; ++k) s += cMp[jj][m][k] * ua[m][k];
#pragma unroll
        for (int k = 0; k < 3; ++k) s += cGp[jj][m][k] * uca[m][k];
      }
      X[jj] = s;
      wb[jj] = s + (wb[jj] - Zb[jj]);
    }
    float xa[4][6];
#pragma unroll
    for (int k = 0; k < 6; ++k) xa[0][k] = X[k];
#pragma unroll
    for (int k = 0; k < 6; ++k) xa[1][k] = DXOR1(xa[0][k]);
#pragma unroll
    for (int k = 0; k < 6; ++k) xa[2][k] = DXOR2(xa[0][k]);
#pragma unroll
    for (int k = 0; k < 6; ++k) xa[3][k] = DXOR2(xa[1][k]);
#pragma unroll
    for (int tt = 0; tt < 3; ++tt) {
      float s = wc[tt] - Zc[tt];
#pragma unroll
      for (int m = 0; m < 4; ++m)
#pragma unroll
        for (int k = 0; k < 6; ++k) s += cAp[tt][m][k] * xa[m][k];
      wc[tt] = s;
    }
  }

  float2* op = (float2*)(outp + (long)row * 24 + 6 * c);
#pragma unroll
  for (int i = 0; i < 3; ++i)
    op[i] = make_float2(X[2 * i], X[2 * i + 1]);
}

// ---------------------------------------------------------------------------
extern "C" void kernel_launch(void* const* d_in, const int* in_sizes, int n_in,
                              void* d_out, int out_size, void* d_ws, size_t ws_size,
                              hipStream_t stream) {
  const float* state = (const float*)d_in[0];
  const float* Aeq   = (const float*)d_in[1];
  const float* beq   = (const float*)d_in[2];
  const float* Ain   = (const float*)d_in[3];
  const float* bin   = (const float*)d_in[4];
  const float* ub    = (const float*)d_in[5];
  const float* lb    = (const float*)d_in[6];
  const float* W1    = (const float*)d_in[7];
  const float* b1    = (const float*)d_in[8];
  const float* W2    = (const float*)d_in[9];
  const float* b2    = (const float*)d_in[10];
  const float* W3    = (const float*)d_in[11];
  const float* b3    = (const float*)d_in[12];

  const int Bn = in_sizes[0] / 512;            // 16384
  char* ws = (char*)d_ws;
  ushort* stateB = (ushort*)(ws + 0);          // 16384x512 bf16  (16 MB)
  ushort* W1T    = (ushort*)(ws + 16777216);   // 1024x512        (1 MB)
  ushort* W2T    = (ushort*)(ws + 17825792);   // 1024x1024       (2 MB)
  ushort* W3T    = (ushort*)(ws + 19922944);   // 32x1024 (rows>=24 zero)
  float*  cbuf   = (float*) (ws + 19988480);   // 1224 f32
  ushort* H1     = (ushort*)(ws + 21565440);   // 16384x1024 bf16 (32 MB)
  ushort* H2     = (ushort*)(ws + 55119872);   // 16384x1024 bf16 (32 MB)
  float*  rawb   = (float*)d_out;              // gemm3 out = admm in (in-place)

  const int n4 = (Bn * 512) / 4;
  convert_bf16<<<(n4 + 255) / 256, 256, 0, stream>>>(state, stateB, n4);
  transpose_f32_bf16<<<dim3(32, 16), 256, 0, stream>>>(W1, W1T, 512, 1024, 1024);
  transpose_f32_bf16<<<dim3(32, 32), 256, 0, stream>>>(W2, W2T, 1024, 1024, 1024);
  transpose_f32_bf16<<<dim3(1, 32),  256, 0, stream>>>(W3, W3T, 1024, 24, 32);
  setup_admm<<<1, 256, 0, stream>>>(Aeq, beq, Ain, bin, ub, lb, cbuf);

  gemm_bt<128, 128, 2, 2, 4, 4, 0><<<dim3(8, Bn / 128), 256, 0, stream>>>(
      stateB, W1T, b1, H1, 512, 1024, 1024);
  gemm_bt<128, 128, 2, 2, 4, 4, 0><<<dim3(8, Bn / 128), 256, 0, stream>>>(
      H1, W2T, b2, H2, 1024, 1024, 1024);
  gemm_bt<64, 32, 4, 1, 1, 2, 1><<<dim3(1, Bn / 64), 256, 0, stream>>>(
      H2, W3T, b3, rawb, 1024, 24, 24);

  admm_kernel<<<Bn / 64, 256, 0, stream>>>(rawb, cbuf, (float*)d_out);
}

// Round 9
// 328.693 us; speedup vs baseline: 4.9403x; 1.0112x over previous
//
#include <hip/hip_runtime.h>

using uint = unsigned int;
using ushort = unsigned short;

typedef __attribute__((ext_vector_type(8))) short bf16x8;
typedef __attribute__((ext_vector_type(4))) float f32x4;

#define ADMM_ITERS 100
#define RHO_C 1.0f
#define SIGMA_C 1e-6f

__device__ inline ushort f2bf(float f) {
  union { float f; uint u; } c; c.f = f;
  uint u = c.u;
  uint r = (u + 0x7fffu + ((u >> 16) & 1u)) >> 16;
  return (ushort)r;
}

// quad_perm DPP cross-lane: result[l] = src[l^1] / src[l^2]. VALU pipe, no LDS.
template<int CTRL> __device__ inline float movd(float x) {
  return __int_as_float(__builtin_amdgcn_mov_dpp(__float_as_int(x), CTRL, 0xf, 0xf, true));
}
#define DXOR1(x) movd<0xB1>(x)   // quad_perm [1,0,3,2]
#define DXOR2(x) movd<0x4E>(x)   // quad_perm [2,3,0,1]

// Value-level register pin: makes a loaded constant NON-REMATERIALIZABLE so
// the allocator keeps it live instead of re-loading it inside the loop.
// Non-volatile, no memory operands -> cannot block alloca promotion (the
// round-3/4 failure used volatile asm on the loop pointer; this is different).
#define PIN(x) asm("" : "+v"(x))

__device__ inline void gload_lds16(const void* g, void* l) {
  __builtin_amdgcn_global_load_lds(
      (const __attribute__((address_space(1))) void*)g,
      (__attribute__((address_space(3))) void*)l, 16, 0, 0);
}

// ---------------------------------------------------------------------------
// f32 -> bf16 elementwise convert (4 elems/thread, float4 loads)
// ---------------------------------------------------------------------------
__global__ void convert_bf16(const float* __restrict__ in, ushort* __restrict__ out, int n4) {
  int i = blockIdx.x * blockDim.x + threadIdx.x;
  if (i >= n4) return;
  float4 v = ((const float4*)in)[i];
  uint2 p;
  p.x = (uint)f2bf(v.x) | ((uint)f2bf(v.y) << 16);
  p.y = (uint)f2bf(v.z) | ((uint)f2bf(v.w) << 16);
  ((uint2*)out)[i] = p;
}

// ---------------------------------------------------------------------------
// f32 transpose -> bf16: out[c][r] = bf16(in[r][c]); rows c in [C,Cout) zeroed.
// ---------------------------------------------------------------------------
__global__ void transpose_f32_bf16(const float* __restrict__ in, ushort* __restrict__ out,
                                   int R, int C, int Cout) {
  __shared__ float t[32][33];
  const int c0 = blockIdx.x * 32, r0 = blockIdx.y * 32;
  const int tx = threadIdx.x & 31, ty = threadIdx.x >> 5;
  for (int rr = ty; rr < 32; rr += 8) {
    int r = r0 + rr, c = c0 + tx;
    float v = 0.0f;
    if (r < R && c < C) v = in[(long)r * C + c];
    t[rr][tx] = v;
  }
  __syncthreads();
  for (int rr = ty; rr < 32; rr += 8) {
    int c = c0 + rr, r = r0 + tx;
    if (c < Cout && r < R) out[(long)c * R + r] = f2bf(t[tx][rr]);
  }
}

// ---------------------------------------------------------------------------
// ADMM constants. cbuf layout (f32), total 1224:
//   Minv[24x24] @0 | A12[12x24] @576 | G = Minv*A12^T [24x12] @864 |
//   lc[12] @1152 | uc[12] @1164 | lb[24] @1176 | ub[24] @1200
// Minv = inv((1+SIGMA+2*RHO)I + RHO*(Aeq^T Aeq + A^T A)) via Gauss-Jordan.
// ---------------------------------------------------------------------------
__global__ void setup_admm(const float* __restrict__ Aeq, const float* __restrict__ beq,
                           const float* __restrict__ A, const float* __restrict__ b,
                           const float* __restrict__ ub, const float* __restrict__ lb,
                           float* __restrict__ cbuf) {
  __shared__ float Aug[24][48];
  __shared__ float A12[12 * 24];
  __shared__ float fac[24];
  const int t = threadIdx.x;
  if (t < 96)  A12[t] = Aeq[t];          // rows 0-3
  if (t < 192) A12[96 + t] = A[t];       // rows 4-11
  __syncthreads();
  for (int idx = t; idx < 576; idx += 256) {
    int j = idx / 24, k = idx % 24;
    float s = (j == k) ? (1.0f + SIGMA_C + 2.0f * RHO_C) : 0.0f;
    for (int r = 0; r < 12; ++r) s += RHO_C * A12[r * 24 + j] * A12[r * 24 + k];
    Aug[j][k] = s;
    Aug[j][24 + k] = (j == k) ? 1.0f : 0.0f;
  }
  __syncthreads();
  for (int p = 0; p < 24; ++p) {
    float rp = 1.0f / Aug[p][p];
    if (t < 24) fac[t] = Aug[t][p];
    __syncthreads();
    if (t < 48) Aug[p][t] *= rp;
    __syncthreads();
    for (int idx = t; idx < 24 * 48; idx += 256) {
      int r = idx / 48, c = idx % 48;
      if (r != p) Aug[r][c] -= fac[r] * Aug[p][c];
    }
    __syncthreads();
  }
  for (int idx = t; idx < 576; idx += 256) cbuf[idx] = Aug[idx / 24][24 + idx % 24];
  for (int idx = t; idx < 288; idx += 256) cbuf[576 + idx] = A12[idx];
  // G[j][r] = sum_k Minv[j][k] * A12[r][k]
  for (int idx = t; idx < 288; idx += 256) {
    int j = idx / 12, r = idx % 12;
    float s = 0.0f;
    for (int k = 0; k < 24; ++k) s += Aug[j][24 + k] * A12[r * 24 + k];
    cbuf[864 + idx] = s;
  }
  if (t < 12) {
    float lv, uv;
    if (t < 4) { lv = beq[t]; uv = lv; }
    else       { lv = -INFINITY; uv = b[t - 4]; }
    cbuf[1152 + t] = lv;
    cbuf[1164 + t] = uv;
  }
  if (t < 24) {
    cbuf[1176 + t] = lb[t];
    cbuf[1200 + t] = ub[t];
  }
}

// ---------------------------------------------------------------------------
// bf16 GEMM, C = A[M,K] * Bt[N,K]^T — m97-style staging (round-8 verified:
// bank conflicts -> 0, MfmaUtil up, gemms dropped out of top-5).
// ---------------------------------------------------------------------------
template<int BM, int BN, int WM, int WN, int TM, int TN, int MODE>
__global__ __launch_bounds__(256) void gemm_bt(
    const ushort* __restrict__ A, const ushort* __restrict__ Bt,
    const float* __restrict__ bias, void* __restrict__ Cout_,
    int K, int ldc, int nvalid) {
  __shared__ char lds[(BM + BN) * 64];
  char* ldsA = lds;
  char* ldsB = lds + BM * 64;

  const int tid = threadIdx.x;
  const int wave = tid >> 6;
  const int lane = tid & 63;
  const int blockM = blockIdx.y * BM;
  const int blockN = blockIdx.x * BN;
  const int wm = (wave / WN) * (TM * 16);
  const int wn = (wave % WN) * (TN * 16);

  f32x4 acc[TM][TN] = {};

  const int l15 = lane & 15;
  const int kq = lane >> 4;
  constexpr int AI = BM / 16;
  constexpr int TOT = (BM + BN) / 16;
  const int srow = lane >> 2;
  const int kb = (lane & 3) ^ ((srow >> 1) & 3);

  for (int k0 = 0; k0 < K; k0 += 32) {
    for (int inst = wave; inst < TOT; inst += 4) {
      const bool isA = inst < AI;
      const int i = isA ? inst : inst - AI;
      const ushort* gp = (isA ? A : Bt)
          + (long)((isA ? blockM : blockN) + i * 16 + srow) * K + (k0 + kb * 8);
      char* lp = (isA ? ldsA : ldsB) + i * 1024;
      gload_lds16(gp, lp);
    }
    __syncthreads();

    bf16x8 af[TM], bfr[TN];
#pragma unroll
    for (int i = 0; i < TM; ++i) {
      int r = wm + i * 16 + l15;
      int ch = kq ^ ((r >> 1) & 3);
      af[i] = *(const bf16x8*)(ldsA + r * 64 + ch * 16);
    }
#pragma unroll
    for (int j = 0; j < TN; ++j) {
      int r = wn + j * 16 + l15;
      int ch = kq ^ ((r >> 1) & 3);
      bfr[j] = *(const bf16x8*)(ldsB + r * 64 + ch * 16);
    }
#pragma unroll
    for (int i = 0; i < TM; ++i)
#pragma unroll
      for (int j = 0; j < TN; ++j)
        acc[i][j] = __builtin_amdgcn_mfma_f32_16x16x32_bf16(af[i], bfr[j], acc[i][j], 0, 0, 0);
    __syncthreads();
  }

  const int ro = lane >> 4;
#pragma unroll
  for (int i = 0; i < TM; ++i) {
#pragma unroll
    for (int j = 0; j < TN; ++j) {
      const int col = blockN + wn + j * 16 + l15;
      float bv;
      if (MODE == 0) bv = bias[col];
      else bv = (col < nvalid) ? bias[col] : 0.0f;
#pragma unroll
      for (int r = 0; r < 4; ++r) {
        const int row = blockM + wm + i * 16 + ro * 4 + r;
        float v = acc[i][j][r] + bv;
        if (MODE == 0) {
          v = fmaxf(v, 0.0f);
          ((ushort*)Cout_)[(long)row * ldc + col] = f2bf(v);
        } else {
          if (col < nvalid) ((float*)Cout_)[(long)row * ldc + col] = v;
        }
      }
    }
  }
}

// ---------------------------------------------------------------------------
// ADMM, 4 lanes/row, constants register-resident AND register-PINNED.
// Round-8 diagnosis: VGPR_Count=208 vs ~306 live constants -> LLVM
// rematerialized (re-loaded) constants inside the loop; at 1 wave/SIMD the
// L1/L2 reload latency is unhidden (~1700 stall cyc/iter, VALUBusy 73%).
// PIN() makes each constant non-rematerializable -> allocator must keep it
// live (budget 512 via launch_bounds(256,1); need ~440).
// ---------------------------------------------------------------------------
__global__ __launch_bounds__(256, 1) void admm_kernel(
    const float* raw, const float* __restrict__ cbuf, float* outp) {
  const int tid = threadIdx.x;
  const int lane = tid & 63;
  const int c = lane & 3;
  const int row = blockIdx.x * 64 + (tid >> 6) * 16 + (lane >> 2);

  float cMp[6][4][6];   // Minv[6c+jj][6(c^m)+kk]
  float cGp[6][4][3];   // G[6c+jj][3(c^m)+tt]
  float cAp[3][4][6];   // A12[3c+tt][6(c^m)+kk]
#pragma unroll
  for (int jj = 0; jj < 6; ++jj)
#pragma unroll
    for (int m = 0; m < 4; ++m) {
      const float2* p = (const float2*)(cbuf + (6 * c + jj) * 24 + 6 * (c ^ m));
#pragma unroll
      for (int h = 0; h < 3; ++h) {
        float2 v = p[h];
        cMp[jj][m][2 * h] = v.x; cMp[jj][m][2 * h + 1] = v.y;
      }
      const float* g = cbuf + 864 + (6 * c + jj) * 12 + 3 * (c ^ m);
#pragma unroll
      for (int h = 0; h < 3; ++h) cGp[jj][m][h] = g[h];
    }
#pragma unroll
  for (int tt = 0; tt < 3; ++tt)
#pragma unroll
    for (int m = 0; m < 4; ++m) {
      const float2* p = (const float2*)(cbuf + 576 + (3 * c + tt) * 24 + 6 * (c ^ m));
#pragma unroll
      for (int h = 0; h < 3; ++h) {
        float2 v = p[h];
        cAp[tt][m][2 * h] = v.x; cAp[tt][m][2 * h + 1] = v.y;
      }
    }
  float lbv[6], ubv[6], lcb[3], ucb[3];
#pragma unroll
  for (int jj = 0; jj < 6; ++jj) {
    lbv[jj] = cbuf[1176 + 6 * c + jj];
    ubv[jj] = cbuf[1200 + 6 * c + jj];
  }
#pragma unroll
  for (int tt = 0; tt < 3; ++tt) {
    lcb[tt] = cbuf[1152 + 3 * c + tt];
    ucb[tt] = cbuf[1164 + 3 * c + tt];
  }

  // ---- pin all constants into registers (non-rematerializable) ------------
#pragma unroll
  for (int jj = 0; jj < 6; ++jj)
#pragma unroll
    for (int m = 0; m < 4; ++m) {
#pragma unroll
      for (int k = 0; k < 6; ++k) PIN(cMp[jj][m][k]);
#pragma unroll
      for (int k = 0; k < 3; ++k) PIN(cGp[jj][m][k]);
    }
#pragma unroll
  for (int tt = 0; tt < 3; ++tt)
#pragma unroll
    for (int m = 0; m < 4; ++m)
#pragma unroll
      for (int k = 0; k < 6; ++k) PIN(cAp[tt][m][k]);
#pragma unroll
  for (int jj = 0; jj < 6; ++jj) { PIN(lbv[jj]); PIN(ubv[jj]); }
#pragma unroll
  for (int tt = 0; tt < 3; ++tt) { PIN(lcb[tt]); PIN(ucb[tt]); }

  float qv[6];
  {
    const float2* rp = (const float2*)(raw + (long)row * 24 + 6 * c);
#pragma unroll
    for (int i = 0; i < 3; ++i) { float2 v = rp[i]; qv[2 * i] = v.x; qv[2 * i + 1] = v.y; }
  }
  float ga[4][6];
#pragma unroll
  for (int k = 0; k < 6; ++k) ga[0][k] = qv[k];
#pragma unroll
  for (int k = 0; k < 6; ++k) ga[1][k] = DXOR1(ga[0][k]);
#pragma unroll
  for (int k = 0; k < 6; ++k) ga[2][k] = DXOR2(ga[0][k]);
#pragma unroll
  for (int k = 0; k < 6; ++k) ga[3][k] = DXOR2(ga[1][k]);

  float qM[6], X[6], wb[6], wc[3];
#pragma unroll
  for (int jj = 0; jj < 6; ++jj) {
    float s = 0.0f;
#pragma unroll
    for (int m = 0; m < 4; ++m)
#pragma unroll
      for (int k = 0; k < 6; ++k) s += cMp[jj][m][k] * ga[m][k];
    qM[jj] = s; X[jj] = s; wb[jj] = s;
  }
#pragma unroll
  for (int k = 0; k < 6; ++k) ga[0][k] = X[k];
#pragma unroll
  for (int k = 0; k < 6; ++k) ga[1][k] = DXOR1(ga[0][k]);
#pragma unroll
  for (int k = 0; k < 6; ++k) ga[2][k] = DXOR2(ga[0][k]);
#pragma unroll
  for (int k = 0; k < 6; ++k) ga[3][k] = DXOR2(ga[1][k]);
#pragma unroll
  for (int tt = 0; tt < 3; ++tt) {
    float s = 0.0f;
#pragma unroll
    for (int m = 0; m < 4; ++m)
#pragma unroll
      for (int k = 0; k < 6; ++k) s += cAp[tt][m][k] * ga[m][k];
    wc[tt] = s;
  }

#pragma unroll 1
  for (int it = 1; it < ADMM_ITERS; ++it) {
    float Zb[6], Zc[3], ub2[6], ucv[3];
#pragma unroll
    for (int jj = 0; jj < 6; ++jj) {
      Zb[jj] = fminf(fmaxf(wb[jj], lbv[jj]), ubv[jj]);
      ub2[jj] = 2.0f * (2.0f * Zb[jj] - wb[jj]);
    }
#pragma unroll
    for (int tt = 0; tt < 3; ++tt) {
      Zc[tt] = fminf(fmaxf(wc[tt], lcb[tt]), ucb[tt]);
      ucv[tt] = 2.0f * Zc[tt] - wc[tt];
    }
    float ua[4][6], uca[4][3];
#pragma unroll
    for (int k = 0; k < 6; ++k) ua[0][k] = ub2[k];
#pragma unroll
    for (int k = 0; k < 6; ++k) ua[1][k] = DXOR1(ua[0][k]);
#pragma unroll
    for (int k = 0; k < 6; ++k) ua[2][k] = DXOR2(ua[0][k]);
#pragma unroll
    for (int k = 0; k < 6; ++k) ua[3][k] = DXOR2(ua[1][k]);
#pragma unroll
    for (int k = 0; k < 3; ++k) uca[0][k] = ucv[k];
#pragma unroll
    for (int k = 0; k < 3; ++k) uca[1][k] = DXOR1(uca[0][k]);
#pragma unroll
    for (int k = 0; k < 3; ++k) uca[2][k] = DXOR2(uca[0][k]);
#pragma unroll
    for (int k = 0; k < 3; ++k) uca[3][k] = DXOR2(uca[1][k]);

#pragma unroll
    for (int jj = 0; jj < 6; ++jj) {
      float s = qM[jj];
#pragma unroll
      for (int m = 0; m < 4; ++m) {
#pragma unroll
        for (int k = 0; k < 6; ++k) s += cMp[jj][m][k] * ua[m][k];
#pragma unroll
        for (int k = 0; k < 3; ++k) s += cGp[jj][m][k] * uca[m][k];
      }
      X[jj] = s;
      wb[jj] = s + (wb[jj] - Zb[jj]);
    }
    float xa[4][6];
#pragma unroll
    for (int k = 0; k < 6; ++k) xa[0][k] = X[k];
#pragma unroll
    for (int k = 0; k < 6; ++k) xa[1][k] = DXOR1(xa[0][k]);
#pragma unroll
    for (int k = 0; k < 6; ++k) xa[2][k] = DXOR2(xa[0][k]);
#pragma unroll
    for (int k = 0; k < 6; ++k) xa[3][k] = DXOR2(xa[1][k]);
#pragma unroll
    for (int tt = 0; tt < 3; ++tt) {
      float s = wc[tt] - Zc[tt];
#pragma unroll
      for (int m = 0; m < 4; ++m)
#pragma unroll
        for (int k = 0; k < 6; ++k) s += cAp[tt][m][k] * xa[m][k];
      wc[tt] = s;
    }
  }

  float2* op = (float2*)(outp + (long)row * 24 + 6 * c);
#pragma unroll
  for (int i = 0; i < 3; ++i)
    op[i] = make_float2(X[2 * i], X[2 * i + 1]);
}

// ---------------------------------------------------------------------------
extern "C" void kernel_launch(void* const* d_in, const int* in_sizes, int n_in,
                              void* d_out, int out_size, void* d_ws, size_t ws_size,
                              hipStream_t stream) {
  const float* state = (const float*)d_in[0];
  const float* Aeq   = (const float*)d_in[1];
  const float* beq   = (const float*)d_in[2];
  const float* Ain   = (const float*)d_in[3];
  const float* bin   = (const float*)d_in[4];
  const float* ub    = (const float*)d_in[5];
  const float* lb    = (const float*)d_in[6];
  const float* W1    = (const float*)d_in[7];
  const float* b1    = (const float*)d_in[8];
  const float* W2    = (const float*)d_in[9];
  const float* b2    = (const float*)d_in[10];
  const float* W3    = (const float*)d_in[11];
  const float* b3    = (const float*)d_in[12];

  const int Bn = in_sizes[0] / 512;            // 16384
  char* ws = (char*)d_ws;
  ushort* stateB = (ushort*)(ws + 0);          // 16384x512 bf16  (16 MB)
  ushort* W1T    = (ushort*)(ws + 16777216);   // 1024x512        (1 MB)
  ushort* W2T    = (ushort*)(ws + 17825792);   // 1024x1024       (2 MB)
  ushort* W3T    = (ushort*)(ws + 19922944);   // 32x1024 (rows>=24 zero)
  float*  cbuf   = (float*) (ws + 19988480);   // 1224 f32
  ushort* H1     = (ushort*)(ws + 21565440);   // 16384x1024 bf16 (32 MB)
  ushort* H2     = (ushort*)(ws + 55119872);   // 16384x1024 bf16 (32 MB)
  float*  rawb   = (float*)d_out;              // gemm3 out = admm in (in-place)

  const int n4 = (Bn * 512) / 4;
  convert_bf16<<<(n4 + 255) / 256, 256, 0, stream>>>(state, stateB, n4);
  transpose_f32_bf16<<<dim3(32, 16), 256, 0, stream>>>(W1, W1T, 512, 1024, 1024);
  transpose_f32_bf16<<<dim3(32, 32), 256, 0, stream>>>(W2, W2T, 1024, 1024, 1024);
  transpose_f32_bf16<<<dim3(1, 32),  256, 0, stream>>>(W3, W3T, 1024, 24, 32);
  setup_admm<<<1, 256, 0, stream>>>(Aeq, beq, Ain, bin, ub, lb, cbuf);

  gemm_bt<128, 128, 2, 2, 4, 4, 0><<<dim3(8, Bn / 128), 256, 0, stream>>>(
      stateB, W1T, b1, H1, 512, 1024, 1024);
  gemm_bt<128, 128, 2, 2, 4, 4, 0><<<dim3(8, Bn / 128), 256, 0, stream>>>(
      H1, W2T, b2, H2, 1024, 1024, 1024);
  gemm_bt<64, 32, 4, 1, 1, 2, 1><<<dim3(1, Bn / 64), 256, 0, stream>>>(
      H2, W3T, b3, rawb, 1024, 24, 24);

  admm_kernel<<<Bn / 64, 256, 0, stream>>>(rawb, cbuf, (float*)d_out);
}